// Round 4
// baseline (333.786 us; speedup 1.0000x reference)
//
#include <hip/hip_runtime.h>
#include <hip/hip_bf16.h>

#define B_ 2
#define T_ 2048
#define E_ 1024
#define H_ 16
#define D_ 64
#define F_ 3072
#define M_ 4096        // B_*T_
#define VT_STRIDE 2080 // padded V^T row stride (breaks 4KB L1-set aliasing)
#define QSCALE 0.1803368801111f  // D^-0.5 * log2(e): softmax runs in exp2 domain
#define THR_LOG2 11.5f           // defer-max threshold (= 8 in ln domain)

typedef __attribute__((ext_vector_type(8))) short short8v;
typedef __attribute__((ext_vector_type(4))) short short4v;
typedef __attribute__((ext_vector_type(4))) float float4v;

#if __has_builtin(__builtin_amdgcn_exp2f)
#define EXP2(x) __builtin_amdgcn_exp2f(x)
#else
#define EXP2(x) exp2f(x)
#endif

// packed fp32x2 -> bf16x2 (v_cvt_pk_bf16_f32, RNE)
__device__ __forceinline__ unsigned cvtpk(float lo, float hi) {
    union { __hip_bfloat162 h; unsigned u; } x;
    x.h = __float22bfloat162_rn(float2{lo, hi});
    return x.u;
}
__device__ __forceinline__ ushort f2bf(float f) { return (ushort)cvtpk(f, f); }

// ---- fp32 -> bf16 conversion, 4 elems per thread ----
__global__ void cvt_kernel(const float* __restrict__ in, ushort* __restrict__ out, int n4) {
    int i = blockIdx.x * blockDim.x + threadIdx.x;
    if (i >= n4) return;
    float4 v = ((const float4*)in)[i];
    uint2 o;
    o.x = cvtpk(v.x, v.y);
    o.y = cvtpk(v.z, v.w);
    ((uint2*)out)[i] = o;
}

// ---- GEMM: C[M][N] = A[M][K] * Bt[N][K]^T  (both bf16, K multiple of 32) ----
// MODE 0: qkv epilogue (bias, q-scale; q,k -> [B][H][T][D]; v -> [B][H][D][VT_STRIDE])
// MODE 1: fp32 out epilogue (bias)
template <int MODE>
__global__ __launch_bounds__(256) void gemm_bt(const ushort* __restrict__ A,
                                               const ushort* __restrict__ Bt,
                                               const float* __restrict__ bias,
                                               void* __restrict__ Cout,
                                               int Ndim, int K) {
    int lane = threadIdx.x & 63;
    int w = threadIdx.x >> 6;
    int wr = w >> 1, wc = w & 1;
    int mb = blockIdx.x * 128 + wr * 64;
    int nb = blockIdx.y * 128 + wc * 64;
    int r15 = lane & 15, g = lane >> 4;

    const ushort* Abase = A + (size_t)(mb + r15) * K + g * 8;
    const ushort* Bbase = Bt + (size_t)(nb + r15) * K + g * 8;

    float4v acc[4][4] = {};
    for (int k0 = 0; k0 < K; k0 += 32) {
        short8v af[4], bf[4];
#pragma unroll
        for (int r = 0; r < 4; ++r)
            af[r] = *(const short8v*)(Abase + (size_t)r * 16 * K + k0);
#pragma unroll
        for (int c = 0; c < 4; ++c)
            bf[c] = *(const short8v*)(Bbase + (size_t)c * 16 * K + k0);
#pragma unroll
        for (int r = 0; r < 4; ++r)
#pragma unroll
            for (int c = 0; c < 4; ++c)
                acc[r][c] = __builtin_amdgcn_mfma_f32_16x16x32_bf16(af[r], bf[c], acc[r][c], 0, 0, 0);
    }

    if (MODE == 0) {
        ushort* qkv = (ushort*)Cout;
#pragma unroll
        for (int r = 0; r < 4; ++r)
#pragma unroll
            for (int c = 0; c < 4; ++c)
#pragma unroll
                for (int ri = 0; ri < 4; ++ri) {
                    int m = mb + r * 16 + g * 4 + ri;
                    int n = nb + c * 16 + r15;
                    float v = acc[r][c][ri] + bias[n];
                    int which = n >> 10;          // 0:q 1:k 2:v
                    int e = n & 1023;
                    if (which == 0) v *= QSCALE;  // D^-0.5 * log2e
                    int h = e >> 6, d = e & 63;
                    int b = m >> 11, t = m & 2047;
                    size_t addr;
                    if (which == 2)  // V transposed + padded: [B][H][D][VT_STRIDE]
                        addr = (size_t)2 * M_ * E_ +
                               ((size_t)(b * H_ + h) * D_ + d) * VT_STRIDE + t;
                    else
                        addr = (size_t)which * M_ * E_ +
                               ((size_t)(b * H_ + h) * T_ + t) * D_ + d;
                    qkv[addr] = f2bf(v);
                }
    } else {
        float* out = (float*)Cout;
#pragma unroll
        for (int r = 0; r < 4; ++r)
#pragma unroll
            for (int c = 0; c < 4; ++c)
#pragma unroll
                for (int ri = 0; ri < 4; ++ri) {
                    int m = mb + r * 16 + g * 4 + ri;
                    int n = nb + c * 16 + r15;
                    out[(size_t)m * Ndim + n] = acc[r][c][ri] + bias[n];
                }
    }
}

// ---- flash attention: 1 block = (head, 128 q-rows); wave = 32 q-rows (2 subtiles) ----
// S^T = mfma(K_frag, Q_frag): C-layout == A-layout of P for the PV mfma.
// Softmax in exp2 domain (q pre-scaled by log2e). Steady state has ZERO
// cross-lane ops: per-lane defer-max check, per-lane partial row-sums
// (corr is uniform within a 4-lane q-group), reduced once at the end.
__global__ __launch_bounds__(256) void attn_kernel(const ushort* __restrict__ qkv,
                                                   ushort* __restrict__ Ob) {
    int lane = threadIdx.x & 63;
    int w = threadIdx.x >> 6;
    int bh = blockIdx.x >> 4;   // b*H + h  (16 q-tiles per head)
    int qt = blockIdx.x & 15;
    int r15 = lane & 15, g = lane >> 4;
    int qb = qt * 128 + w * 32;

    const ushort* Qh = qkv + (size_t)bh * T_ * D_;
    const ushort* Kh = qkv + (size_t)M_ * E_ + (size_t)bh * T_ * D_;
    const ushort* Vt = qkv + (size_t)2 * M_ * E_ + (size_t)bh * D_ * VT_STRIDE;

    const ushort* QrowA = Qh + (size_t)(qb + r15) * D_ + g * 8;
    short8v qfA0 = *(const short8v*)(QrowA);
    short8v qfA1 = *(const short8v*)(QrowA + 32);
    short8v qfB0 = *(const short8v*)(QrowA + 16 * D_);
    short8v qfB1 = *(const short8v*)(QrowA + 16 * D_ + 32);

    float4v oaccA[4] = {}, oaccB[4] = {};
    float mA = -1e30f, lA = 0.f;
    float mB = -1e30f, lB = 0.f;

    // loop-carried pointers
    const ushort* Kp = Kh + (size_t)r15 * D_ + g * 8;
    const ushort* vp0 = Vt + (size_t)(0 * 16 + r15) * VT_STRIDE + g * 4;
    const ushort* vp1 = Vt + (size_t)(1 * 16 + r15) * VT_STRIDE + g * 4;
    const ushort* vp2 = Vt + (size_t)(2 * 16 + r15) * VT_STRIDE + g * 4;
    const ushort* vp3 = Vt + (size_t)(3 * 16 + r15) * VT_STRIDE + g * 4;

    auto softmax_step = [&](const float4v& s0, const float4v& s1, float& m_run,
                            float& l_run, float4v* oacc, short8v& pf) {
        float tmax = fmaxf(fmaxf(fmaxf(s0[0], s0[1]), fmaxf(s0[2], s0[3])),
                           fmaxf(fmaxf(s1[0], s1[1]), fmaxf(s1[2], s1[3])));
        if (!__all(tmax - m_run <= THR_LOG2)) {   // rare: rescale path
            float tr = fmaxf(tmax, __shfl_xor(tmax, 16));
            tr = fmaxf(tr, __shfl_xor(tr, 32));
            float mnew = fmaxf(m_run, tr);
            float corr = EXP2(m_run - mnew);      // uniform within 4-lane q-group
            float c0 = __shfl(corr, g * 4 + 0);
            float c1 = __shfl(corr, g * 4 + 1);
            float c2 = __shfl(corr, g * 4 + 2);
            float c3 = __shfl(corr, g * 4 + 3);
#pragma unroll
            for (int c = 0; c < 4; ++c) {
                oacc[c][0] *= c0; oacc[c][1] *= c1;
                oacc[c][2] *= c2; oacc[c][3] *= c3;
            }
            l_run *= corr;
            m_run = mnew;
        }
        float p0 = EXP2(s0[0] - m_run), p1 = EXP2(s0[1] - m_run);
        float p2 = EXP2(s0[2] - m_run), p3 = EXP2(s0[3] - m_run);
        float p4 = EXP2(s1[0] - m_run), p5 = EXP2(s1[1] - m_run);
        float p6 = EXP2(s1[2] - m_run), p7 = EXP2(s1[3] - m_run);
        l_run += ((p0 + p1) + (p2 + p3)) + ((p4 + p5) + (p6 + p7));  // per-lane partial
        union { short8v v; unsigned u[4]; } pu;
        pu.u[0] = cvtpk(p0, p1); pu.u[1] = cvtpk(p2, p3);
        pu.u[2] = cvtpk(p4, p5); pu.u[3] = cvtpk(p6, p7);
        pf = pu.v;
    };

    for (int kt = 0; kt < T_ / 32; ++kt) {
        short8v k00 = *(const short8v*)(Kp);
        short8v k01 = *(const short8v*)(Kp + 32);
        short8v k10 = *(const short8v*)(Kp + 16 * D_);
        short8v k11 = *(const short8v*)(Kp + 16 * D_ + 32);
        Kp += 32 * D_;

        float4v stA0 = {}, stA1 = {}, stB0 = {}, stB1 = {};
        stA0 = __builtin_amdgcn_mfma_f32_16x16x32_bf16(k00, qfA0, stA0, 0, 0, 0);
        stA0 = __builtin_amdgcn_mfma_f32_16x16x32_bf16(k01, qfA1, stA0, 0, 0, 0);
        stA1 = __builtin_amdgcn_mfma_f32_16x16x32_bf16(k10, qfA0, stA1, 0, 0, 0);
        stA1 = __builtin_amdgcn_mfma_f32_16x16x32_bf16(k11, qfA1, stA1, 0, 0, 0);
        stB0 = __builtin_amdgcn_mfma_f32_16x16x32_bf16(k00, qfB0, stB0, 0, 0, 0);
        stB0 = __builtin_amdgcn_mfma_f32_16x16x32_bf16(k01, qfB1, stB0, 0, 0, 0);
        stB1 = __builtin_amdgcn_mfma_f32_16x16x32_bf16(k10, qfB0, stB1, 0, 0, 0);
        stB1 = __builtin_amdgcn_mfma_f32_16x16x32_bf16(k11, qfB1, stB1, 0, 0, 0);
        // lane holds S^T[key = 16*tile + g*4 + ri][q = r15] per subtile

        // issue V loads early: latency hides under softmax VALU
        short4v v00 = *(const short4v*)(vp0);
        short4v v01 = *(const short4v*)(vp0 + 16);
        short4v v10 = *(const short4v*)(vp1);
        short4v v11 = *(const short4v*)(vp1 + 16);
        short4v v20 = *(const short4v*)(vp2);
        short4v v21 = *(const short4v*)(vp2 + 16);
        short4v v30 = *(const short4v*)(vp3);
        short4v v31 = *(const short4v*)(vp3 + 16);
        vp0 += 32; vp1 += 32; vp2 += 32; vp3 += 32;

        short8v pfA, pfB;
        softmax_step(stA0, stA1, mA, lA, oaccA, pfA);
        softmax_step(stB0, stB1, mB, lB, oaccB, pfB);

        short8v vf0 = __builtin_shufflevector(v00, v01, 0, 1, 2, 3, 4, 5, 6, 7);
        short8v vf1 = __builtin_shufflevector(v10, v11, 0, 1, 2, 3, 4, 5, 6, 7);
        short8v vf2 = __builtin_shufflevector(v20, v21, 0, 1, 2, 3, 4, 5, 6, 7);
        short8v vf3 = __builtin_shufflevector(v30, v31, 0, 1, 2, 3, 4, 5, 6, 7);
        oaccA[0] = __builtin_amdgcn_mfma_f32_16x16x32_bf16(pfA, vf0, oaccA[0], 0, 0, 0);
        oaccB[0] = __builtin_amdgcn_mfma_f32_16x16x32_bf16(pfB, vf0, oaccB[0], 0, 0, 0);
        oaccA[1] = __builtin_amdgcn_mfma_f32_16x16x32_bf16(pfA, vf1, oaccA[1], 0, 0, 0);
        oaccB[1] = __builtin_amdgcn_mfma_f32_16x16x32_bf16(pfB, vf1, oaccB[1], 0, 0, 0);
        oaccA[2] = __builtin_amdgcn_mfma_f32_16x16x32_bf16(pfA, vf2, oaccA[2], 0, 0, 0);
        oaccB[2] = __builtin_amdgcn_mfma_f32_16x16x32_bf16(pfB, vf2, oaccB[2], 0, 0, 0);
        oaccA[3] = __builtin_amdgcn_mfma_f32_16x16x32_bf16(pfA, vf3, oaccA[3], 0, 0, 0);
        oaccB[3] = __builtin_amdgcn_mfma_f32_16x16x32_bf16(pfB, vf3, oaccB[3], 0, 0, 0);
    }

    // final cross-lane reduce of the deferred row-sum partials
    lA += __shfl_xor(lA, 16); lA += __shfl_xor(lA, 32);
    lB += __shfl_xor(lB, 16); lB += __shfl_xor(lB, 32);

    int b = bh >> 4, h = bh & 15;
    {
        float i0 = 1.f / __shfl(lA, g * 4 + 0), i1 = 1.f / __shfl(lA, g * 4 + 1);
        float i2 = 1.f / __shfl(lA, g * 4 + 2), i3 = 1.f / __shfl(lA, g * 4 + 3);
#pragma unroll
        for (int c = 0; c < 4; ++c) {
            size_t base = ((size_t)b * T_ + qb + g * 4) * E_ + h * 64 + c * 16 + r15;
            Ob[base]          = f2bf(oaccA[c][0] * i0);
            Ob[base + E_]     = f2bf(oaccA[c][1] * i1);
            Ob[base + 2 * E_] = f2bf(oaccA[c][2] * i2);
            Ob[base + 3 * E_] = f2bf(oaccA[c][3] * i3);
        }
    }
    {
        float i0 = 1.f / __shfl(lB, g * 4 + 0), i1 = 1.f / __shfl(lB, g * 4 + 1);
        float i2 = 1.f / __shfl(lB, g * 4 + 2), i3 = 1.f / __shfl(lB, g * 4 + 3);
#pragma unroll
        for (int c = 0; c < 4; ++c) {
            size_t base = ((size_t)b * T_ + qb + 16 + g * 4) * E_ + h * 64 + c * 16 + r15;
            Ob[base]          = f2bf(oaccB[c][0] * i0);
            Ob[base + E_]     = f2bf(oaccB[c][1] * i1);
            Ob[base + 2 * E_] = f2bf(oaccB[c][2] * i2);
            Ob[base + 3 * E_] = f2bf(oaccB[c][3] * i3);
        }
    }
}

extern "C" void kernel_launch(void* const* d_in, const int* in_sizes, int n_in,
                              void* d_out, int out_size, void* d_ws, size_t ws_size,
                              hipStream_t stream) {
    const float* query = (const float*)d_in[0];
    const float* Wqkv  = (const float*)d_in[1];
    const float* bqkv  = (const float*)d_in[2];
    const float* Wo    = (const float*)d_in[3];
    const float* bo    = (const float*)d_in[4];
    float* out = (float*)d_out;

    // workspace (bf16 elems), ~42 MB total. Ob aliases Xb (Xb dead after GEMM1).
    ushort* Xb    = (ushort*)d_ws;                        // M_*E_ (8 MB)
    ushort* Wqkvb = Xb + (size_t)M_ * E_;                 // F_*E_ (6 MB)
    ushort* Wob   = Wqkvb + (size_t)F_ * E_;              // E_*E_ (2 MB)
    ushort* QKVb  = Wob + (size_t)E_ * E_;                // 2*M_*E_ + B*H*D*VT_STRIDE
    ushort* Ob    = Xb;                                   // alias: [B*T][E]

    cvt_kernel<<<(M_ * E_ / 4 + 255) / 256, 256, 0, stream>>>(query, Xb, M_ * E_ / 4);
    cvt_kernel<<<(F_ * E_ / 4 + 255) / 256, 256, 0, stream>>>(Wqkv, Wqkvb, F_ * E_ / 4);
    cvt_kernel<<<(E_ * E_ / 4 + 255) / 256, 256, 0, stream>>>(Wo, Wob, E_ * E_ / 4);

    gemm_bt<0><<<dim3(M_ / 128, F_ / 128), 256, 0, stream>>>(Xb, Wqkvb, bqkv, QKVb, F_, E_);
    attn_kernel<<<(B_ * H_) * (T_ / 128), 256, 0, stream>>>(QKVb, Ob);
    gemm_bt<1><<<dim3(M_ / 128, E_ / 128), 256, 0, stream>>>(Ob, Wob, bo, out, E_, E_);
}

// Round 5
// 332.903 us; speedup vs baseline: 1.0027x; 1.0027x over previous
//
#include <hip/hip_runtime.h>
#include <hip/hip_bf16.h>

#define B_ 2
#define T_ 2048
#define E_ 1024
#define H_ 16
#define D_ 64
#define F_ 3072
#define M_ 4096        // B_*T_
#define VT_STRIDE 2080 // padded V^T row stride (breaks 4KB L1-set aliasing)
#define QSCALE 0.1803368801111f  // D^-0.5 * log2(e): softmax runs in exp2 domain
#define THR_LOG2 11.5f           // defer-max threshold (= 8 in ln domain)

typedef __attribute__((ext_vector_type(8))) short short8v;
typedef __attribute__((ext_vector_type(4))) short short4v;
typedef __attribute__((ext_vector_type(4))) float float4v;

#if __has_builtin(__builtin_amdgcn_exp2f)
#define EXP2(x) __builtin_amdgcn_exp2f(x)
#else
#define EXP2(x) exp2f(x)
#endif

// packed fp32x2 -> bf16x2 (v_cvt_pk_bf16_f32, RNE)
__device__ __forceinline__ unsigned cvtpk(float lo, float hi) {
    union { __hip_bfloat162 h; unsigned u; } x;
    x.h = __float22bfloat162_rn(float2{lo, hi});
    return x.u;
}
__device__ __forceinline__ ushort f2bf(float f) { return (ushort)cvtpk(f, f); }

// ---- fp32 -> bf16 conversion, 4 elems per thread ----
__global__ void cvt_kernel(const float* __restrict__ in, ushort* __restrict__ out, int n4) {
    int i = blockIdx.x * blockDim.x + threadIdx.x;
    if (i >= n4) return;
    float4 v = ((const float4*)in)[i];
    uint2 o;
    o.x = cvtpk(v.x, v.y);
    o.y = cvtpk(v.z, v.w);
    ((uint2*)out)[i] = o;
}

// ---- GEMM: C[M][N] = A[M][K] * Bt[N][K]^T  (both bf16, K multiple of 32) ----
// MODE 0: qkv epilogue (bias, q-scale; q,k -> [B][H][T][D]; v -> [B][H][D][VT_STRIDE])
// MODE 1: fp32 out epilogue (bias)
template <int MODE>
__global__ __launch_bounds__(256) void gemm_bt(const ushort* __restrict__ A,
                                               const ushort* __restrict__ Bt,
                                               const float* __restrict__ bias,
                                               void* __restrict__ Cout,
                                               int Ndim, int K) {
    int lane = threadIdx.x & 63;
    int w = threadIdx.x >> 6;
    int wr = w >> 1, wc = w & 1;
    int mb = blockIdx.x * 128 + wr * 64;
    int nb = blockIdx.y * 128 + wc * 64;
    int r15 = lane & 15, g = lane >> 4;

    const ushort* Abase = A + (size_t)(mb + r15) * K + g * 8;
    const ushort* Bbase = Bt + (size_t)(nb + r15) * K + g * 8;

    float4v acc[4][4] = {};
    for (int k0 = 0; k0 < K; k0 += 32) {
        short8v af[4], bf[4];
#pragma unroll
        for (int r = 0; r < 4; ++r)
            af[r] = *(const short8v*)(Abase + (size_t)r * 16 * K + k0);
#pragma unroll
        for (int c = 0; c < 4; ++c)
            bf[c] = *(const short8v*)(Bbase + (size_t)c * 16 * K + k0);
#pragma unroll
        for (int r = 0; r < 4; ++r)
#pragma unroll
            for (int c = 0; c < 4; ++c)
                acc[r][c] = __builtin_amdgcn_mfma_f32_16x16x32_bf16(af[r], bf[c], acc[r][c], 0, 0, 0);
    }

    if (MODE == 0) {
        ushort* qkv = (ushort*)Cout;
#pragma unroll
        for (int r = 0; r < 4; ++r)
#pragma unroll
            for (int c = 0; c < 4; ++c)
#pragma unroll
                for (int ri = 0; ri < 4; ++ri) {
                    int m = mb + r * 16 + g * 4 + ri;
                    int n = nb + c * 16 + r15;
                    float v = acc[r][c][ri] + bias[n];
                    int which = n >> 10;          // 0:q 1:k 2:v
                    int e = n & 1023;
                    if (which == 0) v *= QSCALE;  // D^-0.5 * log2e
                    int h = e >> 6, d = e & 63;
                    int b = m >> 11, t = m & 2047;
                    size_t addr;
                    if (which == 2)  // V transposed + padded: [B][H][D][VT_STRIDE]
                        addr = (size_t)2 * M_ * E_ +
                               ((size_t)(b * H_ + h) * D_ + d) * VT_STRIDE + t;
                    else
                        addr = (size_t)which * M_ * E_ +
                               ((size_t)(b * H_ + h) * T_ + t) * D_ + d;
                    qkv[addr] = f2bf(v);
                }
    } else {
        float* out = (float*)Cout;
#pragma unroll
        for (int r = 0; r < 4; ++r)
#pragma unroll
            for (int c = 0; c < 4; ++c)
#pragma unroll
                for (int ri = 0; ri < 4; ++ri) {
                    int m = mb + r * 16 + g * 4 + ri;
                    int n = nb + c * 16 + r15;
                    out[(size_t)m * Ndim + n] = acc[r][c][ri] + bias[n];
                }
    }
}

// ---- flash attention: 1 block = (head, 128 q-rows); wave = 32 q-rows (2 subtiles) ----
// S^T = mfma(K_frag, Q_frag): C-layout == A-layout of P for the PV mfma.
// XCD-grouped heads (4 heads/XCD -> K,V L2-resident), depth-1 register
// prefetch of K/V tiles, setprio around MFMA clusters.
__global__ __launch_bounds__(256) void attn_kernel(const ushort* __restrict__ qkv,
                                                   ushort* __restrict__ Ob) {
    int lane = threadIdx.x & 63;
    int w = threadIdx.x >> 6;
    int bid = blockIdx.x;
    // XCD swizzle: hardware round-robins dispatch index over 8 XCDs.
    // Give each XCD 4 whole heads so K/V (4 x 512KB = 2MB) stays in its L2.
    int slot = bid >> 3;
    int bh = (bid & 7) * 4 + (slot >> 4);   // b*H + h
    int qt = slot & 15;
    int r15 = lane & 15, g = lane >> 4;
    int qb = qt * 128 + w * 32;

    const ushort* Qh = qkv + (size_t)bh * T_ * D_;
    const ushort* Kh = qkv + (size_t)M_ * E_ + (size_t)bh * T_ * D_;
    const ushort* Vt = qkv + (size_t)2 * M_ * E_ + (size_t)bh * D_ * VT_STRIDE;

    const ushort* QrowA = Qh + (size_t)(qb + r15) * D_ + g * 8;
    short8v qfA0 = *(const short8v*)(QrowA);
    short8v qfA1 = *(const short8v*)(QrowA + 32);
    short8v qfB0 = *(const short8v*)(QrowA + 16 * D_);
    short8v qfB1 = *(const short8v*)(QrowA + 16 * D_ + 32);

    float4v oaccA[4] = {}, oaccB[4] = {};
    float mA = -1e30f, lA = 0.f;
    float mB = -1e30f, lB = 0.f;

    const ushort* KpB = Kh + (size_t)r15 * D_ + g * 8;
    const ushort* vB0 = Vt + (size_t)(0 * 16 + r15) * VT_STRIDE + g * 4;
    const ushort* vB1 = Vt + (size_t)(1 * 16 + r15) * VT_STRIDE + g * 4;
    const ushort* vB2 = Vt + (size_t)(2 * 16 + r15) * VT_STRIDE + g * 4;
    const ushort* vB3 = Vt + (size_t)(3 * 16 + r15) * VT_STRIDE + g * 4;

    struct KT { short8v a, b, c, d; };
    struct VT8 { short4v p0, p1, q0, q1, r0, r1, s0, s1; };

    auto loadK = [&](int kt) {
        const ushort* p = KpB + (size_t)kt * 32 * D_;
        KT t;
        t.a = *(const short8v*)(p);
        t.b = *(const short8v*)(p + 32);
        t.c = *(const short8v*)(p + 16 * D_);
        t.d = *(const short8v*)(p + 16 * D_ + 32);
        return t;
    };
    auto loadV = [&](int kt) {
        int off = kt * 32;
        VT8 t;
        t.p0 = *(const short4v*)(vB0 + off); t.p1 = *(const short4v*)(vB0 + off + 16);
        t.q0 = *(const short4v*)(vB1 + off); t.q1 = *(const short4v*)(vB1 + off + 16);
        t.r0 = *(const short4v*)(vB2 + off); t.r1 = *(const short4v*)(vB2 + off + 16);
        t.s0 = *(const short4v*)(vB3 + off); t.s1 = *(const short4v*)(vB3 + off + 16);
        return t;
    };

    auto softmax_step = [&](const float4v& s0, const float4v& s1, float& m_run,
                            float& l_run, float4v* oacc, short8v& pf) {
        float tmax = fmaxf(fmaxf(fmaxf(s0[0], s0[1]), fmaxf(s0[2], s0[3])),
                           fmaxf(fmaxf(s1[0], s1[1]), fmaxf(s1[2], s1[3])));
        if (!__all(tmax - m_run <= THR_LOG2)) {   // rare: rescale path
            float tr = fmaxf(tmax, __shfl_xor(tmax, 16));
            tr = fmaxf(tr, __shfl_xor(tr, 32));
            float mnew = fmaxf(m_run, tr);
            float corr = EXP2(m_run - mnew);      // uniform within 4-lane q-group
            float c0 = __shfl(corr, g * 4 + 0);
            float c1 = __shfl(corr, g * 4 + 1);
            float c2 = __shfl(corr, g * 4 + 2);
            float c3 = __shfl(corr, g * 4 + 3);
#pragma unroll
            for (int c = 0; c < 4; ++c) {
                oacc[c][0] *= c0; oacc[c][1] *= c1;
                oacc[c][2] *= c2; oacc[c][3] *= c3;
            }
            l_run *= corr;
            m_run = mnew;
        }
        float p0 = EXP2(s0[0] - m_run), p1 = EXP2(s0[1] - m_run);
        float p2 = EXP2(s0[2] - m_run), p3 = EXP2(s0[3] - m_run);
        float p4 = EXP2(s1[0] - m_run), p5 = EXP2(s1[1] - m_run);
        float p6 = EXP2(s1[2] - m_run), p7 = EXP2(s1[3] - m_run);
        l_run += ((p0 + p1) + (p2 + p3)) + ((p4 + p5) + (p6 + p7));  // per-lane partial
        union { short8v v; unsigned u[4]; } pu;
        pu.u[0] = cvtpk(p0, p1); pu.u[1] = cvtpk(p2, p3);
        pu.u[2] = cvtpk(p4, p5); pu.u[3] = cvtpk(p6, p7);
        pf = pu.v;
    };

    auto process = [&](const KT& K, const VT8& V) {
        float4v stA0 = {}, stA1 = {}, stB0 = {}, stB1 = {};
        __builtin_amdgcn_s_setprio(1);
        stA0 = __builtin_amdgcn_mfma_f32_16x16x32_bf16(K.a, qfA0, stA0, 0, 0, 0);
        stA0 = __builtin_amdgcn_mfma_f32_16x16x32_bf16(K.b, qfA1, stA0, 0, 0, 0);
        stA1 = __builtin_amdgcn_mfma_f32_16x16x32_bf16(K.c, qfA0, stA1, 0, 0, 0);
        stA1 = __builtin_amdgcn_mfma_f32_16x16x32_bf16(K.d, qfA1, stA1, 0, 0, 0);
        stB0 = __builtin_amdgcn_mfma_f32_16x16x32_bf16(K.a, qfB0, stB0, 0, 0, 0);
        stB0 = __builtin_amdgcn_mfma_f32_16x16x32_bf16(K.b, qfB1, stB0, 0, 0, 0);
        stB1 = __builtin_amdgcn_mfma_f32_16x16x32_bf16(K.c, qfB0, stB1, 0, 0, 0);
        stB1 = __builtin_amdgcn_mfma_f32_16x16x32_bf16(K.d, qfB1, stB1, 0, 0, 0);
        __builtin_amdgcn_s_setprio(0);
        // lane holds S^T[key = 16*tile + g*4 + ri][q = r15] per subtile

        short8v pfA, pfB;
        softmax_step(stA0, stA1, mA, lA, oaccA, pfA);
        softmax_step(stB0, stB1, mB, lB, oaccB, pfB);

        short8v vf0 = __builtin_shufflevector(V.p0, V.p1, 0, 1, 2, 3, 4, 5, 6, 7);
        short8v vf1 = __builtin_shufflevector(V.q0, V.q1, 0, 1, 2, 3, 4, 5, 6, 7);
        short8v vf2 = __builtin_shufflevector(V.r0, V.r1, 0, 1, 2, 3, 4, 5, 6, 7);
        short8v vf3 = __builtin_shufflevector(V.s0, V.s1, 0, 1, 2, 3, 4, 5, 6, 7);
        __builtin_amdgcn_s_setprio(1);
        oaccA[0] = __builtin_amdgcn_mfma_f32_16x16x32_bf16(pfA, vf0, oaccA[0], 0, 0, 0);
        oaccB[0] = __builtin_amdgcn_mfma_f32_16x16x32_bf16(pfB, vf0, oaccB[0], 0, 0, 0);
        oaccA[1] = __builtin_amdgcn_mfma_f32_16x16x32_bf16(pfA, vf1, oaccA[1], 0, 0, 0);
        oaccB[1] = __builtin_amdgcn_mfma_f32_16x16x32_bf16(pfB, vf1, oaccB[1], 0, 0, 0);
        oaccA[2] = __builtin_amdgcn_mfma_f32_16x16x32_bf16(pfA, vf2, oaccA[2], 0, 0, 0);
        oaccB[2] = __builtin_amdgcn_mfma_f32_16x16x32_bf16(pfB, vf2, oaccB[2], 0, 0, 0);
        oaccA[3] = __builtin_amdgcn_mfma_f32_16x16x32_bf16(pfA, vf3, oaccA[3], 0, 0, 0);
        oaccB[3] = __builtin_amdgcn_mfma_f32_16x16x32_bf16(pfB, vf3, oaccB[3], 0, 0, 0);
        __builtin_amdgcn_s_setprio(0);
    };

    // depth-1 prefetch, manual 2x unroll (named buffers, no runtime indexing)
    KT kc = loadK(0);
    VT8 vc = loadV(0);
    for (int kt = 0; kt < T_ / 32; kt += 2) {
        KT kn = loadK(kt + 1);
        VT8 vn = loadV(kt + 1);
        process(kc, vc);
        if (kt + 2 < T_ / 32) {
            kc = loadK(kt + 2);
            vc = loadV(kt + 2);
        }
        process(kn, vn);
    }

    // final cross-lane reduce of the deferred row-sum partials
    lA += __shfl_xor(lA, 16); lA += __shfl_xor(lA, 32);
    lB += __shfl_xor(lB, 16); lB += __shfl_xor(lB, 32);

    int b = bh >> 4, h = bh & 15;
    {
        float i0 = 1.f / __shfl(lA, g * 4 + 0), i1 = 1.f / __shfl(lA, g * 4 + 1);
        float i2 = 1.f / __shfl(lA, g * 4 + 2), i3 = 1.f / __shfl(lA, g * 4 + 3);
#pragma unroll
        for (int c = 0; c < 4; ++c) {
            size_t base = ((size_t)b * T_ + qb + g * 4) * E_ + h * 64 + c * 16 + r15;
            Ob[base]          = f2bf(oaccA[c][0] * i0);
            Ob[base + E_]     = f2bf(oaccA[c][1] * i1);
            Ob[base + 2 * E_] = f2bf(oaccA[c][2] * i2);
            Ob[base + 3 * E_] = f2bf(oaccA[c][3] * i3);
        }
    }
    {
        float i0 = 1.f / __shfl(lB, g * 4 + 0), i1 = 1.f / __shfl(lB, g * 4 + 1);
        float i2 = 1.f / __shfl(lB, g * 4 + 2), i3 = 1.f / __shfl(lB, g * 4 + 3);
#pragma unroll
        for (int c = 0; c < 4; ++c) {
            size_t base = ((size_t)b * T_ + qb + 16 + g * 4) * E_ + h * 64 + c * 16 + r15;
            Ob[base]          = f2bf(oaccB[c][0] * i0);
            Ob[base + E_]     = f2bf(oaccB[c][1] * i1);
            Ob[base + 2 * E_] = f2bf(oaccB[c][2] * i2);
            Ob[base + 3 * E_] = f2bf(oaccB[c][3] * i3);
        }
    }
}

extern "C" void kernel_launch(void* const* d_in, const int* in_sizes, int n_in,
                              void* d_out, int out_size, void* d_ws, size_t ws_size,
                              hipStream_t stream) {
    const float* query = (const float*)d_in[0];
    const float* Wqkv  = (const float*)d_in[1];
    const float* bqkv  = (const float*)d_in[2];
    const float* Wo    = (const float*)d_in[3];
    const float* bo    = (const float*)d_in[4];
    float* out = (float*)d_out;

    // workspace (bf16 elems), ~42 MB total. Ob aliases Xb (Xb dead after GEMM1).
    ushort* Xb    = (ushort*)d_ws;                        // M_*E_ (8 MB)
    ushort* Wqkvb = Xb + (size_t)M_ * E_;                 // F_*E_ (6 MB)
    ushort* Wob   = Wqkvb + (size_t)F_ * E_;              // E_*E_ (2 MB)
    ushort* QKVb  = Wob + (size_t)E_ * E_;                // 2*M_*E_ + B*H*D*VT_STRIDE
    ushort* Ob    = Xb;                                   // alias: [B*T][E]

    cvt_kernel<<<(M_ * E_ / 4 + 255) / 256, 256, 0, stream>>>(query, Xb, M_ * E_ / 4);
    cvt_kernel<<<(F_ * E_ / 4 + 255) / 256, 256, 0, stream>>>(Wqkv, Wqkvb, F_ * E_ / 4);
    cvt_kernel<<<(E_ * E_ / 4 + 255) / 256, 256, 0, stream>>>(Wo, Wob, E_ * E_ / 4);

    gemm_bt<0><<<dim3(M_ / 128, F_ / 128), 256, 0, stream>>>(Xb, Wqkvb, bqkv, QKVb, F_, E_);
    attn_kernel<<<(B_ * H_) * (T_ / 128), 256, 0, stream>>>(QKVb, Ob);
    gemm_bt<1><<<dim3(M_ / 128, E_ / 128), 256, 0, stream>>>(Ob, Wob, bo, out, E_, E_);
}

// Round 6
// 309.021 us; speedup vs baseline: 1.0801x; 1.0773x over previous
//
#include <hip/hip_runtime.h>
#include <hip/hip_bf16.h>

#define B_ 2
#define T_ 2048
#define E_ 1024
#define H_ 16
#define D_ 64
#define F_ 3072
#define M_ 4096        // B_*T_
#define VT_STRIDE 2080 // padded V^T row stride (breaks 4KB L1-set aliasing)
#define QSCALE 0.1803368801111f  // D^-0.5 * log2(e): softmax runs in exp2 domain
#define THR_LOG2 11.5f           // defer-max threshold (= 8 in ln domain)

typedef __attribute__((ext_vector_type(8))) short short8v;
typedef __attribute__((ext_vector_type(4))) float float4v;

#if __has_builtin(__builtin_amdgcn_exp2f)
#define EXP2(x) __builtin_amdgcn_exp2f(x)
#else
#define EXP2(x) exp2f(x)
#endif

// packed fp32x2 -> bf16x2 (v_cvt_pk_bf16_f32, RNE)
__device__ __forceinline__ unsigned cvtpk(float lo, float hi) {
    union { __hip_bfloat162 h; unsigned u; } x;
    x.h = __float22bfloat162_rn(float2{lo, hi});
    return x.u;
}
__device__ __forceinline__ ushort f2bf(float f) { return (ushort)cvtpk(f, f); }

// ---- fp32 -> bf16 conversion, 4 elems per thread ----
__global__ void cvt_kernel(const float* __restrict__ in, ushort* __restrict__ out, int n4) {
    int i = blockIdx.x * blockDim.x + threadIdx.x;
    if (i >= n4) return;
    float4 v = ((const float4*)in)[i];
    uint2 o;
    o.x = cvtpk(v.x, v.y);
    o.y = cvtpk(v.z, v.w);
    ((uint2*)out)[i] = o;
}

// ---- GEMM: C[M][N] = A[M][K] * Bt[N][K]^T  (both bf16, K multiple of 32) ----
// MODE 0: qkv epilogue (bias, q-scale; q,k -> [B][H][T][D];
//         v -> [B][H][D][VT_STRIDE] with columns PERMUTED within each
//         64-key block: c64 = ((t>>2)&3)*16 + (t>>4)*4 + (t&3), so the attn
//         PV B-fragment (8 keys per lane) is one contiguous 16B load)
// MODE 1: fp32 out epilogue (bias)
template <int MODE>
__global__ __launch_bounds__(256) void gemm_bt(const ushort* __restrict__ A,
                                               const ushort* __restrict__ Bt,
                                               const float* __restrict__ bias,
                                               void* __restrict__ Cout,
                                               int Ndim, int K) {
    int lane = threadIdx.x & 63;
    int w = threadIdx.x >> 6;
    int wr = w >> 1, wc = w & 1;
    int mb = blockIdx.x * 128 + wr * 64;
    int nb = blockIdx.y * 128 + wc * 64;
    int r15 = lane & 15, g = lane >> 4;

    const ushort* Abase = A + (size_t)(mb + r15) * K + g * 8;
    const ushort* Bbase = Bt + (size_t)(nb + r15) * K + g * 8;

    float4v acc[4][4] = {};
    for (int k0 = 0; k0 < K; k0 += 32) {
        short8v af[4], bf[4];
#pragma unroll
        for (int r = 0; r < 4; ++r)
            af[r] = *(const short8v*)(Abase + (size_t)r * 16 * K + k0);
#pragma unroll
        for (int c = 0; c < 4; ++c)
            bf[c] = *(const short8v*)(Bbase + (size_t)c * 16 * K + k0);
#pragma unroll
        for (int r = 0; r < 4; ++r)
#pragma unroll
            for (int c = 0; c < 4; ++c)
                acc[r][c] = __builtin_amdgcn_mfma_f32_16x16x32_bf16(af[r], bf[c], acc[r][c], 0, 0, 0);
    }

    if (MODE == 0) {
        ushort* qkv = (ushort*)Cout;
#pragma unroll
        for (int r = 0; r < 4; ++r)
#pragma unroll
            for (int c = 0; c < 4; ++c)
#pragma unroll
                for (int ri = 0; ri < 4; ++ri) {
                    int m = mb + r * 16 + g * 4 + ri;
                    int n = nb + c * 16 + r15;
                    float v = acc[r][c][ri] + bias[n];
                    int which = n >> 10;          // 0:q 1:k 2:v
                    int e = n & 1023;
                    if (which == 0) v *= QSCALE;  // D^-0.5 * log2e
                    int h = e >> 6, d = e & 63;
                    int b = m >> 11, t = m & 2047;
                    size_t addr;
                    if (which == 2) {  // V^T, padded + 64-block column perm
                        int tt = t & 63;
                        int c64 = ((tt >> 2) & 3) * 16 + (tt >> 4) * 4 + (tt & 3);
                        int tp = (t & ~63) | c64;
                        addr = (size_t)2 * M_ * E_ +
                               ((size_t)(b * H_ + h) * D_ + d) * VT_STRIDE + tp;
                    } else {
                        addr = (size_t)which * M_ * E_ +
                               ((size_t)(b * H_ + h) * T_ + t) * D_ + d;
                    }
                    qkv[addr] = f2bf(v);
                }
    } else {
        float* out = (float*)Cout;
#pragma unroll
        for (int r = 0; r < 4; ++r)
#pragma unroll
            for (int c = 0; c < 4; ++c)
#pragma unroll
                for (int ri = 0; ri < 4; ++ri) {
                    int m = mb + r * 16 + g * 4 + ri;
                    int n = nb + c * 16 + r15;
                    out[(size_t)m * Ndim + n] = acc[r][c][ri] + bias[n];
                }
    }
}

// ---- flash attention: 1 block = (head, 128 q-rows); wave = 32 q-rows (2 subtiles) ----
// S^T = mfma(K_frag, Q_frag): C-layout == A-layout of P for the PV mfma.
// KVBLK = 64; XCD-grouped heads; depth-1 register double-buffer of K/V
// (launch_bounds(256,2) gives the VGPR headroom so it actually materializes);
// V^T columns pre-permuted so PV B-frags are single 16B loads.
__global__ __launch_bounds__(256, 2) void attn_kernel(const ushort* __restrict__ qkv,
                                                      ushort* __restrict__ Ob) {
    int lane = threadIdx.x & 63;
    int w = threadIdx.x >> 6;
    int bid = blockIdx.x;
    // XCD swizzle: dispatch round-robins over 8 XCDs; give each XCD 4 whole
    // heads so K/V (4 x 512KB = 2MB) stays in its L2.
    int slot = bid >> 3;
    int bh = (bid & 7) * 4 + (slot >> 4);   // b*H + h
    int qt = slot & 15;
    int r15 = lane & 15, g = lane >> 4;
    int qb = qt * 128 + w * 32;

    const ushort* Qh = qkv + (size_t)bh * T_ * D_;
    const ushort* Kh = qkv + (size_t)M_ * E_ + (size_t)bh * T_ * D_;
    const ushort* Vt = qkv + (size_t)2 * M_ * E_ + (size_t)bh * D_ * VT_STRIDE;

    const ushort* QrowA = Qh + (size_t)(qb + r15) * D_ + g * 8;
    short8v qfA0 = *(const short8v*)(QrowA);
    short8v qfA1 = *(const short8v*)(QrowA + 32);
    short8v qfB0 = *(const short8v*)(QrowA + 16 * D_);
    short8v qfB1 = *(const short8v*)(QrowA + 16 * D_ + 32);

    float4v oaccA[4] = {}, oaccB[4] = {};
    float mA = -1e30f, lA = 0.f;
    float mB = -1e30f, lB = 0.f;

    const ushort* Kp0 = Kh + (size_t)r15 * D_ + g * 8;
    const ushort* vr0 = Vt + (size_t)(0 * 16 + r15) * VT_STRIDE + g * 16;
    const ushort* vr1 = Vt + (size_t)(1 * 16 + r15) * VT_STRIDE + g * 16;
    const ushort* vr2 = Vt + (size_t)(2 * 16 + r15) * VT_STRIDE + g * 16;
    const ushort* vr3 = Vt + (size_t)(3 * 16 + r15) * VT_STRIDE + g * 16;

    struct KT  { short8v r0a, r0b, r1a, r1b, r2a, r2b, r3a, r3b; };
    struct VTl { short8v c00, c01, c10, c11, c20, c21, c30, c31; };

    auto loadK = [&](int kt) {
        const ushort* p = Kp0 + (size_t)kt * 64 * D_;
        KT t;
        t.r0a = *(const short8v*)(p);            t.r0b = *(const short8v*)(p + 32);
        t.r1a = *(const short8v*)(p + 16 * D_);  t.r1b = *(const short8v*)(p + 16 * D_ + 32);
        t.r2a = *(const short8v*)(p + 32 * D_);  t.r2b = *(const short8v*)(p + 32 * D_ + 32);
        t.r3a = *(const short8v*)(p + 48 * D_);  t.r3b = *(const short8v*)(p + 48 * D_ + 32);
        return t;
    };
    auto loadV = [&](int kt) {
        int off = kt * 64;
        VTl t;
        t.c00 = *(const short8v*)(vr0 + off); t.c01 = *(const short8v*)(vr0 + off + 8);
        t.c10 = *(const short8v*)(vr1 + off); t.c11 = *(const short8v*)(vr1 + off + 8);
        t.c20 = *(const short8v*)(vr2 + off); t.c21 = *(const short8v*)(vr2 + off + 8);
        t.c30 = *(const short8v*)(vr3 + off); t.c31 = *(const short8v*)(vr3 + off + 8);
        return t;
    };

    auto softmax64 = [&](const float4v& s0, const float4v& s1, const float4v& s2,
                         const float4v& s3, float& m_run, float& l_run,
                         float4v* oacc, short8v& pf0, short8v& pf1) {
        float t0 = fmaxf(fmaxf(s0[0], s0[1]), fmaxf(s0[2], s0[3]));
        float t1 = fmaxf(fmaxf(s1[0], s1[1]), fmaxf(s1[2], s1[3]));
        float t2 = fmaxf(fmaxf(s2[0], s2[1]), fmaxf(s2[2], s2[3]));
        float t3 = fmaxf(fmaxf(s3[0], s3[1]), fmaxf(s3[2], s3[3]));
        float tmax = fmaxf(fmaxf(t0, t1), fmaxf(t2, t3));
        if (!__all(tmax - m_run <= THR_LOG2)) {   // rare: rescale path
            float tr = fmaxf(tmax, __shfl_xor(tmax, 16));
            tr = fmaxf(tr, __shfl_xor(tr, 32));
            float mnew = fmaxf(m_run, tr);
            float corr = EXP2(m_run - mnew);      // uniform within 4-lane q-group
            float c0 = __shfl(corr, g * 4 + 0);
            float c1 = __shfl(corr, g * 4 + 1);
            float c2 = __shfl(corr, g * 4 + 2);
            float c3 = __shfl(corr, g * 4 + 3);
#pragma unroll
            for (int c = 0; c < 4; ++c) {
                oacc[c][0] *= c0; oacc[c][1] *= c1;
                oacc[c][2] *= c2; oacc[c][3] *= c3;
            }
            l_run *= corr;
            m_run = mnew;
        }
        float p0 = EXP2(s0[0] - m_run), p1 = EXP2(s0[1] - m_run);
        float p2 = EXP2(s0[2] - m_run), p3 = EXP2(s0[3] - m_run);
        float p4 = EXP2(s1[0] - m_run), p5 = EXP2(s1[1] - m_run);
        float p6 = EXP2(s1[2] - m_run), p7 = EXP2(s1[3] - m_run);
        float p8 = EXP2(s2[0] - m_run), p9 = EXP2(s2[1] - m_run);
        float pa = EXP2(s2[2] - m_run), pb = EXP2(s2[3] - m_run);
        float pc = EXP2(s3[0] - m_run), pd = EXP2(s3[1] - m_run);
        float pe = EXP2(s3[2] - m_run), pg = EXP2(s3[3] - m_run);
        l_run += (((p0 + p1) + (p2 + p3)) + ((p4 + p5) + (p6 + p7))) +
                 (((p8 + p9) + (pa + pb)) + ((pc + pd) + (pe + pg)));
        union { short8v v; unsigned u[4]; } u0, u1;
        u0.u[0] = cvtpk(p0, p1); u0.u[1] = cvtpk(p2, p3);
        u0.u[2] = cvtpk(p4, p5); u0.u[3] = cvtpk(p6, p7);
        u1.u[0] = cvtpk(p8, p9); u1.u[1] = cvtpk(pa, pb);
        u1.u[2] = cvtpk(pc, pd); u1.u[3] = cvtpk(pe, pg);
        pf0 = u0.v; pf1 = u1.v;
    };

    auto process = [&](const KT& K, const VTl& V) {
        float4v sA0 = {}, sA1 = {}, sA2 = {}, sA3 = {};
        float4v sB0 = {}, sB1 = {}, sB2 = {}, sB3 = {};
        __builtin_amdgcn_s_setprio(1);
        sA0 = __builtin_amdgcn_mfma_f32_16x16x32_bf16(K.r0a, qfA0, sA0, 0, 0, 0);
        sA0 = __builtin_amdgcn_mfma_f32_16x16x32_bf16(K.r0b, qfA1, sA0, 0, 0, 0);
        sA1 = __builtin_amdgcn_mfma_f32_16x16x32_bf16(K.r1a, qfA0, sA1, 0, 0, 0);
        sA1 = __builtin_amdgcn_mfma_f32_16x16x32_bf16(K.r1b, qfA1, sA1, 0, 0, 0);
        sA2 = __builtin_amdgcn_mfma_f32_16x16x32_bf16(K.r2a, qfA0, sA2, 0, 0, 0);
        sA2 = __builtin_amdgcn_mfma_f32_16x16x32_bf16(K.r2b, qfA1, sA2, 0, 0, 0);
        sA3 = __builtin_amdgcn_mfma_f32_16x16x32_bf16(K.r3a, qfA0, sA3, 0, 0, 0);
        sA3 = __builtin_amdgcn_mfma_f32_16x16x32_bf16(K.r3b, qfA1, sA3, 0, 0, 0);
        sB0 = __builtin_amdgcn_mfma_f32_16x16x32_bf16(K.r0a, qfB0, sB0, 0, 0, 0);
        sB0 = __builtin_amdgcn_mfma_f32_16x16x32_bf16(K.r0b, qfB1, sB0, 0, 0, 0);
        sB1 = __builtin_amdgcn_mfma_f32_16x16x32_bf16(K.r1a, qfB0, sB1, 0, 0, 0);
        sB1 = __builtin_amdgcn_mfma_f32_16x16x32_bf16(K.r1b, qfB1, sB1, 0, 0, 0);
        sB2 = __builtin_amdgcn_mfma_f32_16x16x32_bf16(K.r2a, qfB0, sB2, 0, 0, 0);
        sB2 = __builtin_amdgcn_mfma_f32_16x16x32_bf16(K.r2b, qfB1, sB2, 0, 0, 0);
        sB3 = __builtin_amdgcn_mfma_f32_16x16x32_bf16(K.r3a, qfB0, sB3, 0, 0, 0);
        sB3 = __builtin_amdgcn_mfma_f32_16x16x32_bf16(K.r3b, qfB1, sB3, 0, 0, 0);
        __builtin_amdgcn_s_setprio(0);
        // lane holds S^T[key = 16*sub + g*4 + ri][q = r15] per subtile

        short8v pA0, pA1, pB0, pB1;
        softmax64(sA0, sA1, sA2, sA3, mA, lA, oaccA, pA0, pA1);
        softmax64(sB0, sB1, sB2, sB3, mB, lB, oaccB, pB0, pB1);

        __builtin_amdgcn_s_setprio(1);
        oaccA[0] = __builtin_amdgcn_mfma_f32_16x16x32_bf16(pA0, V.c00, oaccA[0], 0, 0, 0);
        oaccA[0] = __builtin_amdgcn_mfma_f32_16x16x32_bf16(pA1, V.c01, oaccA[0], 0, 0, 0);
        oaccB[0] = __builtin_amdgcn_mfma_f32_16x16x32_bf16(pB0, V.c00, oaccB[0], 0, 0, 0);
        oaccB[0] = __builtin_amdgcn_mfma_f32_16x16x32_bf16(pB1, V.c01, oaccB[0], 0, 0, 0);
        oaccA[1] = __builtin_amdgcn_mfma_f32_16x16x32_bf16(pA0, V.c10, oaccA[1], 0, 0, 0);
        oaccA[1] = __builtin_amdgcn_mfma_f32_16x16x32_bf16(pA1, V.c11, oaccA[1], 0, 0, 0);
        oaccB[1] = __builtin_amdgcn_mfma_f32_16x16x32_bf16(pB0, V.c10, oaccB[1], 0, 0, 0);
        oaccB[1] = __builtin_amdgcn_mfma_f32_16x16x32_bf16(pB1, V.c11, oaccB[1], 0, 0, 0);
        oaccA[2] = __builtin_amdgcn_mfma_f32_16x16x32_bf16(pA0, V.c20, oaccA[2], 0, 0, 0);
        oaccA[2] = __builtin_amdgcn_mfma_f32_16x16x32_bf16(pA1, V.c21, oaccA[2], 0, 0, 0);
        oaccB[2] = __builtin_amdgcn_mfma_f32_16x16x32_bf16(pB0, V.c20, oaccB[2], 0, 0, 0);
        oaccB[2] = __builtin_amdgcn_mfma_f32_16x16x32_bf16(pB1, V.c21, oaccB[2], 0, 0, 0);
        oaccA[3] = __builtin_amdgcn_mfma_f32_16x16x32_bf16(pA0, V.c30, oaccA[3], 0, 0, 0);
        oaccA[3] = __builtin_amdgcn_mfma_f32_16x16x32_bf16(pA1, V.c31, oaccA[3], 0, 0, 0);
        oaccB[3] = __builtin_amdgcn_mfma_f32_16x16x32_bf16(pB0, V.c30, oaccB[3], 0, 0, 0);
        oaccB[3] = __builtin_amdgcn_mfma_f32_16x16x32_bf16(pB1, V.c31, oaccB[3], 0, 0, 0);
        __builtin_amdgcn_s_setprio(0);
    };

    // depth-1 prefetch, manual 2x unroll (named buffers, no runtime indexing)
    KT  kc = loadK(0);
    VTl vc = loadV(0);
    for (int kt = 0; kt < T_ / 64; kt += 2) {
        KT  kn = loadK(kt + 1);
        VTl vn = loadV(kt + 1);
        process(kc, vc);
        if (kt + 2 < T_ / 64) {
            kc = loadK(kt + 2);
            vc = loadV(kt + 2);
        }
        process(kn, vn);
    }

    // final cross-lane reduce of the deferred row-sum partials
    lA += __shfl_xor(lA, 16); lA += __shfl_xor(lA, 32);
    lB += __shfl_xor(lB, 16); lB += __shfl_xor(lB, 32);

    int b = bh >> 4, h = bh & 15;
    {
        float i0 = 1.f / __shfl(lA, g * 4 + 0), i1 = 1.f / __shfl(lA, g * 4 + 1);
        float i2 = 1.f / __shfl(lA, g * 4 + 2), i3 = 1.f / __shfl(lA, g * 4 + 3);
#pragma unroll
        for (int c = 0; c < 4; ++c) {
            size_t base = ((size_t)b * T_ + qb + g * 4) * E_ + h * 64 + c * 16 + r15;
            Ob[base]          = f2bf(oaccA[c][0] * i0);
            Ob[base + E_]     = f2bf(oaccA[c][1] * i1);
            Ob[base + 2 * E_] = f2bf(oaccA[c][2] * i2);
            Ob[base + 3 * E_] = f2bf(oaccA[c][3] * i3);
        }
    }
    {
        float i0 = 1.f / __shfl(lB, g * 4 + 0), i1 = 1.f / __shfl(lB, g * 4 + 1);
        float i2 = 1.f / __shfl(lB, g * 4 + 2), i3 = 1.f / __shfl(lB, g * 4 + 3);
#pragma unroll
        for (int c = 0; c < 4; ++c) {
            size_t base = ((size_t)b * T_ + qb + 16 + g * 4) * E_ + h * 64 + c * 16 + r15;
            Ob[base]          = f2bf(oaccB[c][0] * i0);
            Ob[base + E_]     = f2bf(oaccB[c][1] * i1);
            Ob[base + 2 * E_] = f2bf(oaccB[c][2] * i2);
            Ob[base + 3 * E_] = f2bf(oaccB[c][3] * i3);
        }
    }
}

extern "C" void kernel_launch(void* const* d_in, const int* in_sizes, int n_in,
                              void* d_out, int out_size, void* d_ws, size_t ws_size,
                              hipStream_t stream) {
    const float* query = (const float*)d_in[0];
    const float* Wqkv  = (const float*)d_in[1];
    const float* bqkv  = (const float*)d_in[2];
    const float* Wo    = (const float*)d_in[3];
    const float* bo    = (const float*)d_in[4];
    float* out = (float*)d_out;

    // workspace (bf16 elems), ~41 MB total. Ob aliases Xb (Xb dead after GEMM1).
    ushort* Xb    = (ushort*)d_ws;                        // M_*E_ (8 MB)
    ushort* Wqkvb = Xb + (size_t)M_ * E_;                 // F_*E_ (6 MB)
    ushort* Wob   = Wqkvb + (size_t)F_ * E_;              // E_*E_ (2 MB)
    ushort* QKVb  = Wob + (size_t)E_ * E_;                // 2*M_*E_ + B*H*D*VT_STRIDE
    ushort* Ob    = Xb;                                   // alias: [B*T][E]

    cvt_kernel<<<(M_ * E_ / 4 + 255) / 256, 256, 0, stream>>>(query, Xb, M_ * E_ / 4);
    cvt_kernel<<<(F_ * E_ / 4 + 255) / 256, 256, 0, stream>>>(Wqkv, Wqkvb, F_ * E_ / 4);
    cvt_kernel<<<(E_ * E_ / 4 + 255) / 256, 256, 0, stream>>>(Wo, Wob, E_ * E_ / 4);

    gemm_bt<0><<<dim3(M_ / 128, F_ / 128), 256, 0, stream>>>(Xb, Wqkvb, bqkv, QKVb, F_, E_);
    attn_kernel<<<(B_ * H_) * (T_ / 128), 256, 0, stream>>>(QKVb, Ob);
    gemm_bt<1><<<dim3(M_ / 128, E_ / 128), 256, 0, stream>>>(Ob, Wob, bo, out, E_, E_);
}

// Round 7
// 238.019 us; speedup vs baseline: 1.4024x; 1.2983x over previous
//
#include <hip/hip_runtime.h>
#include <hip/hip_bf16.h>

#define B_ 2
#define T_ 2048
#define E_ 1024
#define H_ 16
#define D_ 64
#define F_ 3072
#define M_ 4096        // B_*T_
#define VT_STRIDE 2080 // padded V^T row stride (breaks 4KB L1-set aliasing)
#define QSCALE 0.1803368801111f  // D^-0.5 * log2(e): softmax runs in exp2 domain
#define THR_LOG2 11.5f           // defer-max threshold (= 8 in ln domain)

typedef __attribute__((ext_vector_type(8))) short short8v;
typedef __attribute__((ext_vector_type(4))) float float4v;

#if __has_builtin(__builtin_amdgcn_exp2f)
#define EXP2(x) __builtin_amdgcn_exp2f(x)
#else
#define EXP2(x) exp2f(x)
#endif

// packed fp32x2 -> bf16x2 (v_cvt_pk_bf16_f32, RNE)
__device__ __forceinline__ unsigned cvtpk(float lo, float hi) {
    union { __hip_bfloat162 h; unsigned u; } x;
    x.h = __float22bfloat162_rn(float2{lo, hi});
    return x.u;
}
__device__ __forceinline__ ushort f2bf(float f) { return (ushort)cvtpk(f, f); }

// ---- fp32 -> bf16 conversion, 4 elems per thread ----
__global__ void cvt_kernel(const float* __restrict__ in, ushort* __restrict__ out, int n4) {
    int i = blockIdx.x * blockDim.x + threadIdx.x;
    if (i >= n4) return;
    float4 v = ((const float4*)in)[i];
    uint2 o;
    o.x = cvtpk(v.x, v.y);
    o.y = cvtpk(v.z, v.w);
    ((uint2*)out)[i] = o;
}

// ---- GEMM: C[M][N] = A[M][K] * Bt[N][K]^T  (bf16, K mult of 64) ----
// m97-class structure: 128x128 tile, BK=64, global_load_lds(16B) staging into
// 32KB LDS, XOR-swizzled (chunk ^= row&7 on 128B rows; swizzle applied on the
// GLOBAL source so the LDS dest stays linear — rule #21), 2-barrier K-loop.
// MODE 0: qkv epilogue (bias, q-scale; q,k -> [B][H][T][D];
//         v -> [B][H][D][VT_STRIDE], columns permuted within 64-key blocks)
// MODE 1: fp32 out epilogue (bias)
template <int MODE>
__global__ __launch_bounds__(256) void gemm_bt(const ushort* __restrict__ A,
                                               const ushort* __restrict__ Bt,
                                               const float* __restrict__ bias,
                                               void* __restrict__ Cout,
                                               int Ndim, int K) {
    __shared__ __attribute__((aligned(16))) char lds[32768]; // A:[0,16K) B:[16K,32K)
    int t = threadIdx.x;
    int lane = t & 63;
    int w = t >> 6;
    int wr = w >> 1, wc = w & 1;
    int bm0 = blockIdx.x * 128, bn0 = blockIdx.y * 128;
    int mb = bm0 + wr * 64;
    int nb = bn0 + wc * 64;
    int r15 = lane & 15, g = lane >> 4;

    // staging: lane l of wave w, issue j covers LDS offset j*4096 + w*1024 + l*16
    //   -> local row = j*32 + w*8 + l/8 (128B rows), swizzled chunk = l&7,
    //      logical chunk = (l&7) ^ (row&7) = (l&7) ^ (l>>3)
    int srow = w * 8 + (lane >> 3);
    int schunk = (lane & 7) ^ (lane >> 3);
    const ushort* Asrc = A + (size_t)(bm0 + srow) * K + schunk * 8;
    const ushort* Bsrc = Bt + (size_t)(bn0 + srow) * K + schunk * 8;

    // frag reads: row_local = (wr|wc)*64 + r*16 + r15, byte = row_local*128 +
    //   (((h*4+g) ^ (r15&7)) << 4)   [row&7 == r15&7 since other terms are x16]
    int rxor7 = r15 & 7;
    int abase = (wr * 64 + r15) * 128;
    int bbase = 16384 + (wc * 64 + r15) * 128;

    float4v acc[4][4] = {};
    for (int k0 = 0; k0 < K; k0 += 64) {
#pragma unroll
        for (int j = 0; j < 4; ++j) {
            __builtin_amdgcn_global_load_lds(
                (const __attribute__((address_space(1))) void*)(Asrc + (size_t)(j * 32) * K + k0),
                (__attribute__((address_space(3))) void*)(lds + j * 4096 + w * 1024),
                16, 0, 0);
            __builtin_amdgcn_global_load_lds(
                (const __attribute__((address_space(1))) void*)(Bsrc + (size_t)(j * 32) * K + k0),
                (__attribute__((address_space(3))) void*)(lds + 16384 + j * 4096 + w * 1024),
                16, 0, 0);
        }
        __syncthreads();  // compiler inserts vmcnt(0): staging complete

        short8v af[4][2], bf[4][2];
#pragma unroll
        for (int r = 0; r < 4; ++r)
#pragma unroll
            for (int h = 0; h < 2; ++h)
                af[r][h] = *(const short8v*)(lds + abase + r * 2048 +
                                             (((h * 4 + g) ^ rxor7) << 4));
#pragma unroll
        for (int c = 0; c < 4; ++c)
#pragma unroll
            for (int h = 0; h < 2; ++h)
                bf[c][h] = *(const short8v*)(lds + bbase + c * 2048 +
                                             (((h * 4 + g) ^ rxor7) << 4));
#pragma unroll
        for (int r = 0; r < 4; ++r)
#pragma unroll
            for (int c = 0; c < 4; ++c) {
                acc[r][c] = __builtin_amdgcn_mfma_f32_16x16x32_bf16(af[r][0], bf[c][0], acc[r][c], 0, 0, 0);
                acc[r][c] = __builtin_amdgcn_mfma_f32_16x16x32_bf16(af[r][1], bf[c][1], acc[r][c], 0, 0, 0);
            }
        __syncthreads();  // all reads done before next stage overwrites
    }

    if (MODE == 0) {
        ushort* qkv = (ushort*)Cout;
#pragma unroll
        for (int r = 0; r < 4; ++r)
#pragma unroll
            for (int c = 0; c < 4; ++c)
#pragma unroll
                for (int ri = 0; ri < 4; ++ri) {
                    int m = mb + r * 16 + g * 4 + ri;
                    int n = nb + c * 16 + r15;
                    float v = acc[r][c][ri] + bias[n];
                    int which = n >> 10;          // 0:q 1:k 2:v
                    int e = n & 1023;
                    if (which == 0) v *= QSCALE;  // D^-0.5 * log2e
                    int h = e >> 6, d = e & 63;
                    int b = m >> 11, tt0 = m & 2047;
                    size_t addr;
                    if (which == 2) {  // V^T, padded + 64-block column perm
                        int tt = tt0 & 63;
                        int c64 = ((tt >> 2) & 3) * 16 + (tt >> 4) * 4 + (tt & 3);
                        int tp = (tt0 & ~63) | c64;
                        addr = (size_t)2 * M_ * E_ +
                               ((size_t)(b * H_ + h) * D_ + d) * VT_STRIDE + tp;
                    } else {
                        addr = (size_t)which * M_ * E_ +
                               ((size_t)(b * H_ + h) * T_ + tt0) * D_ + d;
                    }
                    qkv[addr] = f2bf(v);
                }
    } else {
        float* out = (float*)Cout;
#pragma unroll
        for (int r = 0; r < 4; ++r)
#pragma unroll
            for (int c = 0; c < 4; ++c)
#pragma unroll
                for (int ri = 0; ri < 4; ++ri) {
                    int m = mb + r * 16 + g * 4 + ri;
                    int n = nb + c * 16 + r15;
                    out[(size_t)m * Ndim + n] = acc[r][c][ri] + bias[n];
                }
    }
}

// ---- flash attention: 1 block = (head, 128 q-rows); wave = 32 q-rows (2 subtiles) ----
// S^T = mfma(K_frag, Q_frag): C-layout == A-layout of P for the PV mfma.
// KVBLK = 64; XCD-grouped heads; depth-1 register double-buffer of K/V
// (launch_bounds(256,2) gives the VGPR headroom so it actually materializes);
// V^T columns pre-permuted so PV B-frags are single 16B loads.
__global__ __launch_bounds__(256, 2) void attn_kernel(const ushort* __restrict__ qkv,
                                                      ushort* __restrict__ Ob) {
    int lane = threadIdx.x & 63;
    int w = threadIdx.x >> 6;
    int bid = blockIdx.x;
    // XCD swizzle: dispatch round-robins over 8 XCDs; give each XCD 4 whole
    // heads so K/V (4 x 512KB = 2MB) stays in its L2.
    int slot = bid >> 3;
    int bh = (bid & 7) * 4 + (slot >> 4);   // b*H + h
    int qt = slot & 15;
    int r15 = lane & 15, g = lane >> 4;
    int qb = qt * 128 + w * 32;

    const ushort* Qh = qkv + (size_t)bh * T_ * D_;
    const ushort* Kh = qkv + (size_t)M_ * E_ + (size_t)bh * T_ * D_;
    const ushort* Vt = qkv + (size_t)2 * M_ * E_ + (size_t)bh * D_ * VT_STRIDE;

    const ushort* QrowA = Qh + (size_t)(qb + r15) * D_ + g * 8;
    short8v qfA0 = *(const short8v*)(QrowA);
    short8v qfA1 = *(const short8v*)(QrowA + 32);
    short8v qfB0 = *(const short8v*)(QrowA + 16 * D_);
    short8v qfB1 = *(const short8v*)(QrowA + 16 * D_ + 32);

    float4v oaccA[4] = {}, oaccB[4] = {};
    float mA = -1e30f, lA = 0.f;
    float mB = -1e30f, lB = 0.f;

    const ushort* Kp0 = Kh + (size_t)r15 * D_ + g * 8;
    const ushort* vr0 = Vt + (size_t)(0 * 16 + r15) * VT_STRIDE + g * 16;
    const ushort* vr1 = Vt + (size_t)(1 * 16 + r15) * VT_STRIDE + g * 16;
    const ushort* vr2 = Vt + (size_t)(2 * 16 + r15) * VT_STRIDE + g * 16;
    const ushort* vr3 = Vt + (size_t)(3 * 16 + r15) * VT_STRIDE + g * 16;

    struct KT  { short8v r0a, r0b, r1a, r1b, r2a, r2b, r3a, r3b; };
    struct VTl { short8v c00, c01, c10, c11, c20, c21, c30, c31; };

    auto loadK = [&](int kt) {
        const ushort* p = Kp0 + (size_t)kt * 64 * D_;
        KT t;
        t.r0a = *(const short8v*)(p);            t.r0b = *(const short8v*)(p + 32);
        t.r1a = *(const short8v*)(p + 16 * D_);  t.r1b = *(const short8v*)(p + 16 * D_ + 32);
        t.r2a = *(const short8v*)(p + 32 * D_);  t.r2b = *(const short8v*)(p + 32 * D_ + 32);
        t.r3a = *(const short8v*)(p + 48 * D_);  t.r3b = *(const short8v*)(p + 48 * D_ + 32);
        return t;
    };
    auto loadV = [&](int kt) {
        int off = kt * 64;
        VTl t;
        t.c00 = *(const short8v*)(vr0 + off); t.c01 = *(const short8v*)(vr0 + off + 8);
        t.c10 = *(const short8v*)(vr1 + off); t.c11 = *(const short8v*)(vr1 + off + 8);
        t.c20 = *(const short8v*)(vr2 + off); t.c21 = *(const short8v*)(vr2 + off + 8);
        t.c30 = *(const short8v*)(vr3 + off); t.c31 = *(const short8v*)(vr3 + off + 8);
        return t;
    };

    auto softmax64 = [&](const float4v& s0, const float4v& s1, const float4v& s2,
                         const float4v& s3, float& m_run, float& l_run,
                         float4v* oacc, short8v& pf0, short8v& pf1) {
        float t0 = fmaxf(fmaxf(s0[0], s0[1]), fmaxf(s0[2], s0[3]));
        float t1 = fmaxf(fmaxf(s1[0], s1[1]), fmaxf(s1[2], s1[3]));
        float t2 = fmaxf(fmaxf(s2[0], s2[1]), fmaxf(s2[2], s2[3]));
        float t3 = fmaxf(fmaxf(s3[0], s3[1]), fmaxf(s3[2], s3[3]));
        float tmax = fmaxf(fmaxf(t0, t1), fmaxf(t2, t3));
        if (!__all(tmax - m_run <= THR_LOG2)) {   // rare: rescale path
            float tr = fmaxf(tmax, __shfl_xor(tmax, 16));
            tr = fmaxf(tr, __shfl_xor(tr, 32));
            float mnew = fmaxf(m_run, tr);
            float corr = EXP2(m_run - mnew);      // uniform within 4-lane q-group
            float c0 = __shfl(corr, g * 4 + 0);
            float c1 = __shfl(corr, g * 4 + 1);
            float c2 = __shfl(corr, g * 4 + 2);
            float c3 = __shfl(corr, g * 4 + 3);
#pragma unroll
            for (int c = 0; c < 4; ++c) {
                oacc[c][0] *= c0; oacc[c][1] *= c1;
                oacc[c][2] *= c2; oacc[c][3] *= c3;
            }
            l_run *= corr;
            m_run = mnew;
        }
        float p0 = EXP2(s0[0] - m_run), p1 = EXP2(s0[1] - m_run);
        float p2 = EXP2(s0[2] - m_run), p3 = EXP2(s0[3] - m_run);
        float p4 = EXP2(s1[0] - m_run), p5 = EXP2(s1[1] - m_run);
        float p6 = EXP2(s1[2] - m_run), p7 = EXP2(s1[3] - m_run);
        float p8 = EXP2(s2[0] - m_run), p9 = EXP2(s2[1] - m_run);
        float pa = EXP2(s2[2] - m_run), pb = EXP2(s2[3] - m_run);
        float pc = EXP2(s3[0] - m_run), pd = EXP2(s3[1] - m_run);
        float pe = EXP2(s3[2] - m_run), pg = EXP2(s3[3] - m_run);
        l_run += (((p0 + p1) + (p2 + p3)) + ((p4 + p5) + (p6 + p7))) +
                 (((p8 + p9) + (pa + pb)) + ((pc + pd) + (pe + pg)));
        union { short8v v; unsigned u[4]; } u0, u1;
        u0.u[0] = cvtpk(p0, p1); u0.u[1] = cvtpk(p2, p3);
        u0.u[2] = cvtpk(p4, p5); u0.u[3] = cvtpk(p6, p7);
        u1.u[0] = cvtpk(p8, p9); u1.u[1] = cvtpk(pa, pb);
        u1.u[2] = cvtpk(pc, pd); u1.u[3] = cvtpk(pe, pg);
        pf0 = u0.v; pf1 = u1.v;
    };

    auto process = [&](const KT& K, const VTl& V) {
        float4v sA0 = {}, sA1 = {}, sA2 = {}, sA3 = {};
        float4v sB0 = {}, sB1 = {}, sB2 = {}, sB3 = {};
        __builtin_amdgcn_s_setprio(1);
        sA0 = __builtin_amdgcn_mfma_f32_16x16x32_bf16(K.r0a, qfA0, sA0, 0, 0, 0);
        sA0 = __builtin_amdgcn_mfma_f32_16x16x32_bf16(K.r0b, qfA1, sA0, 0, 0, 0);
        sA1 = __builtin_amdgcn_mfma_f32_16x16x32_bf16(K.r1a, qfA0, sA1, 0, 0, 0);
        sA1 = __builtin_amdgcn_mfma_f32_16x16x32_bf16(K.r1b, qfA1, sA1, 0, 0, 0);
        sA2 = __builtin_amdgcn_mfma_f32_16x16x32_bf16(K.r2a, qfA0, sA2, 0, 0, 0);
        sA2 = __builtin_amdgcn_mfma_f32_16x16x32_bf16(K.r2b, qfA1, sA2, 0, 0, 0);
        sA3 = __builtin_amdgcn_mfma_f32_16x16x32_bf16(K.r3a, qfA0, sA3, 0, 0, 0);
        sA3 = __builtin_amdgcn_mfma_f32_16x16x32_bf16(K.r3b, qfA1, sA3, 0, 0, 0);
        sB0 = __builtin_amdgcn_mfma_f32_16x16x32_bf16(K.r0a, qfB0, sB0, 0, 0, 0);
        sB0 = __builtin_amdgcn_mfma_f32_16x16x32_bf16(K.r0b, qfB1, sB0, 0, 0, 0);
        sB1 = __builtin_amdgcn_mfma_f32_16x16x32_bf16(K.r1a, qfB0, sB1, 0, 0, 0);
        sB1 = __builtin_amdgcn_mfma_f32_16x16x32_bf16(K.r1b, qfB1, sB1, 0, 0, 0);
        sB2 = __builtin_amdgcn_mfma_f32_16x16x32_bf16(K.r2a, qfB0, sB2, 0, 0, 0);
        sB2 = __builtin_amdgcn_mfma_f32_16x16x32_bf16(K.r2b, qfB1, sB2, 0, 0, 0);
        sB3 = __builtin_amdgcn_mfma_f32_16x16x32_bf16(K.r3a, qfB0, sB3, 0, 0, 0);
        sB3 = __builtin_amdgcn_mfma_f32_16x16x32_bf16(K.r3b, qfB1, sB3, 0, 0, 0);
        __builtin_amdgcn_s_setprio(0);
        // lane holds S^T[key = 16*sub + g*4 + ri][q = r15] per subtile

        short8v pA0, pA1, pB0, pB1;
        softmax64(sA0, sA1, sA2, sA3, mA, lA, oaccA, pA0, pA1);
        softmax64(sB0, sB1, sB2, sB3, mB, lB, oaccB, pB0, pB1);

        __builtin_amdgcn_s_setprio(1);
        oaccA[0] = __builtin_amdgcn_mfma_f32_16x16x32_bf16(pA0, V.c00, oaccA[0], 0, 0, 0);
        oaccA[0] = __builtin_amdgcn_mfma_f32_16x16x32_bf16(pA1, V.c01, oaccA[0], 0, 0, 0);
        oaccB[0] = __builtin_amdgcn_mfma_f32_16x16x32_bf16(pB0, V.c00, oaccB[0], 0, 0, 0);
        oaccB[0] = __builtin_amdgcn_mfma_f32_16x16x32_bf16(pB1, V.c01, oaccB[0], 0, 0, 0);
        oaccA[1] = __builtin_amdgcn_mfma_f32_16x16x32_bf16(pA0, V.c10, oaccA[1], 0, 0, 0);
        oaccA[1] = __builtin_amdgcn_mfma_f32_16x16x32_bf16(pA1, V.c11, oaccA[1], 0, 0, 0);
        oaccB[1] = __builtin_amdgcn_mfma_f32_16x16x32_bf16(pB0, V.c10, oaccB[1], 0, 0, 0);
        oaccB[1] = __builtin_amdgcn_mfma_f32_16x16x32_bf16(pB1, V.c11, oaccB[1], 0, 0, 0);
        oaccA[2] = __builtin_amdgcn_mfma_f32_16x16x32_bf16(pA0, V.c20, oaccA[2], 0, 0, 0);
        oaccA[2] = __builtin_amdgcn_mfma_f32_16x16x32_bf16(pA1, V.c21, oaccA[2], 0, 0, 0);
        oaccB[2] = __builtin_amdgcn_mfma_f32_16x16x32_bf16(pB0, V.c20, oaccB[2], 0, 0, 0);
        oaccB[2] = __builtin_amdgcn_mfma_f32_16x16x32_bf16(pB1, V.c21, oaccB[2], 0, 0, 0);
        oaccA[3] = __builtin_amdgcn_mfma_f32_16x16x32_bf16(pA0, V.c30, oaccA[3], 0, 0, 0);
        oaccA[3] = __builtin_amdgcn_mfma_f32_16x16x32_bf16(pA1, V.c31, oaccA[3], 0, 0, 0);
        oaccB[3] = __builtin_amdgcn_mfma_f32_16x16x32_bf16(pB0, V.c30, oaccB[3], 0, 0, 0);
        oaccB[3] = __builtin_amdgcn_mfma_f32_16x16x32_bf16(pB1, V.c31, oaccB[3], 0, 0, 0);
        __builtin_amdgcn_s_setprio(0);
    };

    // depth-1 prefetch, manual 2x unroll (named buffers, no runtime indexing)
    KT  kc = loadK(0);
    VTl vc = loadV(0);
    for (int kt = 0; kt < T_ / 64; kt += 2) {
        KT  kn = loadK(kt + 1);
        VTl vn = loadV(kt + 1);
        process(kc, vc);
        if (kt + 2 < T_ / 64) {
            kc = loadK(kt + 2);
            vc = loadV(kt + 2);
        }
        process(kn, vn);
    }

    // final cross-lane reduce of the deferred row-sum partials
    lA += __shfl_xor(lA, 16); lA += __shfl_xor(lA, 32);
    lB += __shfl_xor(lB, 16); lB += __shfl_xor(lB, 32);

    int b = bh >> 4, h = bh & 15;
    {
        float i0 = 1.f / __shfl(lA, g * 4 + 0), i1 = 1.f / __shfl(lA, g * 4 + 1);
        float i2 = 1.f / __shfl(lA, g * 4 + 2), i3 = 1.f / __shfl(lA, g * 4 + 3);
#pragma unroll
        for (int c = 0; c < 4; ++c) {
            size_t base = ((size_t)b * T_ + qb + g * 4) * E_ + h * 64 + c * 16 + r15;
            Ob[base]          = f2bf(oaccA[c][0] * i0);
            Ob[base + E_]     = f2bf(oaccA[c][1] * i1);
            Ob[base + 2 * E_] = f2bf(oaccA[c][2] * i2);
            Ob[base + 3 * E_] = f2bf(oaccA[c][3] * i3);
        }
    }
    {
        float i0 = 1.f / __shfl(lB, g * 4 + 0), i1 = 1.f / __shfl(lB, g * 4 + 1);
        float i2 = 1.f / __shfl(lB, g * 4 + 2), i3 = 1.f / __shfl(lB, g * 4 + 3);
#pragma unroll
        for (int c = 0; c < 4; ++c) {
            size_t base = ((size_t)b * T_ + qb + 16 + g * 4) * E_ + h * 64 + c * 16 + r15;
            Ob[base]          = f2bf(oaccB[c][0] * i0);
            Ob[base + E_]     = f2bf(oaccB[c][1] * i1);
            Ob[base + 2 * E_] = f2bf(oaccB[c][2] * i2);
            Ob[base + 3 * E_] = f2bf(oaccB[c][3] * i3);
        }
    }
}

extern "C" void kernel_launch(void* const* d_in, const int* in_sizes, int n_in,
                              void* d_out, int out_size, void* d_ws, size_t ws_size,
                              hipStream_t stream) {
    const float* query = (const float*)d_in[0];
    const float* Wqkv  = (const float*)d_in[1];
    const float* bqkv  = (const float*)d_in[2];
    const float* Wo    = (const float*)d_in[3];
    const float* bo    = (const float*)d_in[4];
    float* out = (float*)d_out;

    // workspace (bf16 elems), ~41 MB total. Ob aliases Xb (Xb dead after GEMM1).
    ushort* Xb    = (ushort*)d_ws;                        // M_*E_ (8 MB)
    ushort* Wqkvb = Xb + (size_t)M_ * E_;                 // F_*E_ (6 MB)
    ushort* Wob   = Wqkvb + (size_t)F_ * E_;              // E_*E_ (2 MB)
    ushort* QKVb  = Wob + (size_t)E_ * E_;                // 2*M_*E_ + B*H*D*VT_STRIDE
    ushort* Ob    = Xb;                                   // alias: [B*T][E]

    cvt_kernel<<<(M_ * E_ / 4 + 255) / 256, 256, 0, stream>>>(query, Xb, M_ * E_ / 4);
    cvt_kernel<<<(F_ * E_ / 4 + 255) / 256, 256, 0, stream>>>(Wqkv, Wqkvb, F_ * E_ / 4);
    cvt_kernel<<<(E_ * E_ / 4 + 255) / 256, 256, 0, stream>>>(Wo, Wob, E_ * E_ / 4);

    gemm_bt<0><<<dim3(M_ / 128, F_ / 128), 256, 0, stream>>>(Xb, Wqkvb, bqkv, QKVb, F_, E_);
    attn_kernel<<<(B_ * H_) * (T_ / 128), 256, 0, stream>>>(QKVb, Ob);
    gemm_bt<1><<<dim3(M_ / 128, E_ / 128), 256, 0, stream>>>(Ob, Wob, bo, out, E_, E_);
}

// Round 8
// 197.091 us; speedup vs baseline: 1.6936x; 1.2077x over previous
//
#include <hip/hip_runtime.h>
#include <hip/hip_bf16.h>

#define B_ 2
#define T_ 2048
#define E_ 1024
#define H_ 16
#define D_ 64
#define F_ 3072
#define M_ 4096        // B_*T_
#define VT_STRIDE 2080 // padded V^T row stride (breaks 4KB L1-set aliasing)
#define QSCALE 0.1803368801111f  // D^-0.5 * log2(e): softmax runs in exp2 domain
#define THR_LOG2 11.5f           // defer-max threshold (= 8 in ln domain)

typedef __attribute__((ext_vector_type(8))) short short8v;
typedef __attribute__((ext_vector_type(4))) float float4v;

#if __has_builtin(__builtin_amdgcn_exp2f)
#define EXP2(x) __builtin_amdgcn_exp2f(x)
#else
#define EXP2(x) exp2f(x)
#endif

// packed fp32x2 -> bf16x2 (v_cvt_pk_bf16_f32, RNE)
__device__ __forceinline__ unsigned cvtpk(float lo, float hi) {
    union { __hip_bfloat162 h; unsigned u; } x;
    x.h = __float22bfloat162_rn(float2{lo, hi});
    return x.u;
}
__device__ __forceinline__ ushort f2bf(float f) { return (ushort)cvtpk(f, f); }

// ---- fp32 -> bf16 conversion, 4 elems per thread ----
__global__ void cvt_kernel(const float* __restrict__ in, ushort* __restrict__ out, int n4) {
    int i = blockIdx.x * blockDim.x + threadIdx.x;
    if (i >= n4) return;
    float4 v = ((const float4*)in)[i];
    uint2 o;
    o.x = cvtpk(v.x, v.y);
    o.y = cvtpk(v.z, v.w);
    ((uint2*)out)[i] = o;
}

// ---- GEMM: C[M][N] = A[M][K] * Bt[N][K]^T  (bf16, K mult of 64) ----
// m97-class structure: 128x128 tile, BK=64, global_load_lds(16B) staging into
// 32KB LDS, XOR-swizzled (chunk ^= row&7 on 128B rows; swizzle applied on the
// GLOBAL source so the LDS dest stays linear — rule #21), 2-barrier K-loop.
// MODE 0: qkv epilogue (bias, q-scale; q,k -> [B][H][T][D];
//         v -> [B][H][D][VT_STRIDE], columns permuted within 64-key blocks)
// MODE 1: fp32 out epilogue (bias)
template <int MODE>
__global__ __launch_bounds__(256) void gemm_bt(const ushort* __restrict__ A,
                                               const ushort* __restrict__ Bt,
                                               const float* __restrict__ bias,
                                               void* __restrict__ Cout,
                                               int Ndim, int K) {
    __shared__ __attribute__((aligned(16))) char lds[32768]; // A:[0,16K) B:[16K,32K)
    int t = threadIdx.x;
    int lane = t & 63;
    int w = t >> 6;
    int wr = w >> 1, wc = w & 1;
    int bm0 = blockIdx.x * 128, bn0 = blockIdx.y * 128;
    int mb = bm0 + wr * 64;
    int nb = bn0 + wc * 64;
    int r15 = lane & 15, g = lane >> 4;

    int srow = w * 8 + (lane >> 3);
    int schunk = (lane & 7) ^ (lane >> 3);
    const ushort* Asrc = A + (size_t)(bm0 + srow) * K + schunk * 8;
    const ushort* Bsrc = Bt + (size_t)(bn0 + srow) * K + schunk * 8;

    int rxor7 = r15 & 7;
    int abase = (wr * 64 + r15) * 128;
    int bbase = 16384 + (wc * 64 + r15) * 128;

    float4v acc[4][4] = {};
    for (int k0 = 0; k0 < K; k0 += 64) {
#pragma unroll
        for (int j = 0; j < 4; ++j) {
            __builtin_amdgcn_global_load_lds(
                (const __attribute__((address_space(1))) void*)(Asrc + (size_t)(j * 32) * K + k0),
                (__attribute__((address_space(3))) void*)(lds + j * 4096 + w * 1024),
                16, 0, 0);
            __builtin_amdgcn_global_load_lds(
                (const __attribute__((address_space(1))) void*)(Bsrc + (size_t)(j * 32) * K + k0),
                (__attribute__((address_space(3))) void*)(lds + 16384 + j * 4096 + w * 1024),
                16, 0, 0);
        }
        __syncthreads();

        short8v af[4][2], bf[4][2];
#pragma unroll
        for (int r = 0; r < 4; ++r)
#pragma unroll
            for (int h = 0; h < 2; ++h)
                af[r][h] = *(const short8v*)(lds + abase + r * 2048 +
                                             (((h * 4 + g) ^ rxor7) << 4));
#pragma unroll
        for (int c = 0; c < 4; ++c)
#pragma unroll
            for (int h = 0; h < 2; ++h)
                bf[c][h] = *(const short8v*)(lds + bbase + c * 2048 +
                                             (((h * 4 + g) ^ rxor7) << 4));
#pragma unroll
        for (int r = 0; r < 4; ++r)
#pragma unroll
            for (int c = 0; c < 4; ++c) {
                acc[r][c] = __builtin_amdgcn_mfma_f32_16x16x32_bf16(af[r][0], bf[c][0], acc[r][c], 0, 0, 0);
                acc[r][c] = __builtin_amdgcn_mfma_f32_16x16x32_bf16(af[r][1], bf[c][1], acc[r][c], 0, 0, 0);
            }
        __syncthreads();
    }

    if (MODE == 0) {
        ushort* qkv = (ushort*)Cout;
#pragma unroll
        for (int r = 0; r < 4; ++r)
#pragma unroll
            for (int c = 0; c < 4; ++c)
#pragma unroll
                for (int ri = 0; ri < 4; ++ri) {
                    int m = mb + r * 16 + g * 4 + ri;
                    int n = nb + c * 16 + r15;
                    float v = acc[r][c][ri] + bias[n];
                    int which = n >> 10;          // 0:q 1:k 2:v
                    int e = n & 1023;
                    if (which == 0) v *= QSCALE;  // D^-0.5 * log2e
                    int h = e >> 6, d = e & 63;
                    int b = m >> 11, tt0 = m & 2047;
                    size_t addr;
                    if (which == 2) {  // V^T, padded + 64-block column perm
                        int tt = tt0 & 63;
                        int c64 = ((tt >> 2) & 3) * 16 + (tt >> 4) * 4 + (tt & 3);
                        int tp = (tt0 & ~63) | c64;
                        addr = (size_t)2 * M_ * E_ +
                               ((size_t)(b * H_ + h) * D_ + d) * VT_STRIDE + tp;
                    } else {
                        addr = (size_t)which * M_ * E_ +
                               ((size_t)(b * H_ + h) * T_ + tt0) * D_ + d;
                    }
                    qkv[addr] = f2bf(v);
                }
    } else {
        float* out = (float*)Cout;
#pragma unroll
        for (int r = 0; r < 4; ++r)
#pragma unroll
            for (int c = 0; c < 4; ++c)
#pragma unroll
                for (int ri = 0; ri < 4; ++ri) {
                    int m = mb + r * 16 + g * 4 + ri;
                    int n = nb + c * 16 + r15;
                    out[(size_t)m * Ndim + n] = acc[r][c][ri] + bias[n];
                }
    }
}

// ---- flash attention: 1 block = (head, 128 q-rows); wave = 32 q-rows ----
// KVBLK=64. K/V staged ONCE per block into double-buffered LDS via
// global_load_lds (16B, pre-swizzled global source, linear LDS dest, XOR
// read-side swizzle — rule #21), counted vmcnt(4) + raw s_barrier pipeline
// (loads for the next tile stay in flight across the compute phase).
__global__ __launch_bounds__(256, 2) void attn_kernel(const ushort* __restrict__ qkv,
                                                      ushort* __restrict__ Ob) {
    __shared__ __attribute__((aligned(16))) char lds[32768]; // 2 x (K 8K | V 8K)
    int tid = threadIdx.x;
    int lane = tid & 63;
    int w = tid >> 6;
    int bid = blockIdx.x;
    // XCD swizzle: give each XCD 4 whole heads so K/V (2MB) stays in its L2.
    int slot = bid >> 3;
    int bh = (bid & 7) * 4 + (slot >> 4);   // b*H + h
    int qt = slot & 15;
    int r15 = lane & 15, g = lane >> 4;
    int qb = qt * 128 + w * 32;

    const ushort* Qh = qkv + (size_t)bh * T_ * D_;
    const ushort* Kh = qkv + (size_t)M_ * E_ + (size_t)bh * T_ * D_;
    const ushort* Vt = qkv + (size_t)2 * M_ * E_ + (size_t)bh * D_ * VT_STRIDE;

    const ushort* QrowA = Qh + (size_t)(qb + r15) * D_ + g * 8;
    short8v qfA0 = *(const short8v*)(QrowA);
    short8v qfA1 = *(const short8v*)(QrowA + 32);
    short8v qfB0 = *(const short8v*)(QrowA + 16 * D_);
    short8v qfB1 = *(const short8v*)(QrowA + 16 * D_ + 32);
    // anchor Q loads: drain them now so the staging vmcnt ledger stays exact
    asm volatile("" :: "v"(qfA0), "v"(qfA1), "v"(qfB0), "v"(qfB1));

    float4v oaccA[4] = {}, oaccB[4] = {};
    float mA = -1e30f, lA = 0.f;
    float mB = -1e30f, lB = 0.f;

    // ---- staging precompute: thread tid covers LDS 16B chunk tid*16 (+i*4096)
    //      row = i*32 + (tid>>3), stored chunk = tid&7,
    //      logical chunk = (tid&7) ^ (row&7)
    int srow = tid >> 3;                       // 0..31
    int slc = (tid & 7) ^ (srow & 7);
    const ushort* Ksrc = Kh + (size_t)srow * D_ + slc * 8;
    const ushort* Vsrc = Vt + (size_t)srow * VT_STRIDE + slc * 8;

    auto stage = [&](int kt, int base) {
        const ushort* kp = Ksrc + (size_t)kt * 64 * D_;
        const ushort* vp = Vsrc + kt * 64;
#pragma unroll
        for (int i = 0; i < 2; ++i)
            __builtin_amdgcn_global_load_lds(
                (const __attribute__((address_space(1))) void*)(kp + (size_t)i * 32 * D_),
                (__attribute__((address_space(3))) void*)(lds + base + i * 4096 + tid * 16),
                16, 0, 0);
#pragma unroll
        for (int i = 0; i < 2; ++i)
            __builtin_amdgcn_global_load_lds(
                (const __attribute__((address_space(1))) void*)(vp + (size_t)i * 32 * VT_STRIDE),
                (__attribute__((address_space(3))) void*)(lds + base + 8192 + i * 4096 + tid * 16),
                16, 0, 0);
    };

    // ---- frag read offsets (XOR read-side swizzle) ----
    int rxor = (r15 & 7) << 4;
    int rowb = r15 * 128;
    int kc0 = ((g) << 4) ^ rxor;         // K cols 0..31, lane chunk g
    int kc1 = ((g + 4) << 4) ^ rxor;     // K cols 32..63
    int vc0 = ((2 * g) << 4) ^ rxor;     // V perm'd keys g*16..+7
    int vc1 = ((2 * g + 1) << 4) ^ rxor; // V perm'd keys g*16+8..+15

    auto softmax64 = [&](const float4v& s0, const float4v& s1, const float4v& s2,
                         const float4v& s3, float& m_run, float& l_run,
                         float4v* oacc, short8v& pf0, short8v& pf1) {
        float t0 = fmaxf(fmaxf(s0[0], s0[1]), fmaxf(s0[2], s0[3]));
        float t1 = fmaxf(fmaxf(s1[0], s1[1]), fmaxf(s1[2], s1[3]));
        float t2 = fmaxf(fmaxf(s2[0], s2[1]), fmaxf(s2[2], s2[3]));
        float t3 = fmaxf(fmaxf(s3[0], s3[1]), fmaxf(s3[2], s3[3]));
        float tmax = fmaxf(fmaxf(t0, t1), fmaxf(t2, t3));
        if (!__all(tmax - m_run <= THR_LOG2)) {   // rare: rescale path
            float tr = fmaxf(tmax, __shfl_xor(tmax, 16));
            tr = fmaxf(tr, __shfl_xor(tr, 32));
            float mnew = fmaxf(m_run, tr);
            float corr = EXP2(m_run - mnew);      // uniform within 4-lane q-group
            float c0 = __shfl(corr, g * 4 + 0);
            float c1 = __shfl(corr, g * 4 + 1);
            float c2 = __shfl(corr, g * 4 + 2);
            float c3 = __shfl(corr, g * 4 + 3);
#pragma unroll
            for (int c = 0; c < 4; ++c) {
                oacc[c][0] *= c0; oacc[c][1] *= c1;
                oacc[c][2] *= c2; oacc[c][3] *= c3;
            }
            l_run *= corr;
            m_run = mnew;
        }
        float p0 = EXP2(s0[0] - m_run), p1 = EXP2(s0[1] - m_run);
        float p2 = EXP2(s0[2] - m_run), p3 = EXP2(s0[3] - m_run);
        float p4 = EXP2(s1[0] - m_run), p5 = EXP2(s1[1] - m_run);
        float p6 = EXP2(s1[2] - m_run), p7 = EXP2(s1[3] - m_run);
        float p8 = EXP2(s2[0] - m_run), p9 = EXP2(s2[1] - m_run);
        float pa = EXP2(s2[2] - m_run), pb = EXP2(s2[3] - m_run);
        float pc = EXP2(s3[0] - m_run), pd = EXP2(s3[1] - m_run);
        float pe = EXP2(s3[2] - m_run), pg = EXP2(s3[3] - m_run);
        l_run += (((p0 + p1) + (p2 + p3)) + ((p4 + p5) + (p6 + p7))) +
                 (((p8 + p9) + (pa + pb)) + ((pc + pd) + (pe + pg)));
        union { short8v v; unsigned u[4]; } u0, u1;
        u0.u[0] = cvtpk(p0, p1); u0.u[1] = cvtpk(p2, p3);
        u0.u[2] = cvtpk(p4, p5); u0.u[3] = cvtpk(p6, p7);
        u1.u[0] = cvtpk(p8, p9); u1.u[1] = cvtpk(pa, pb);
        u1.u[2] = cvtpk(pc, pd); u1.u[3] = cvtpk(pe, pg);
        pf0 = u0.v; pf1 = u1.v;
    };

    auto compute = [&](int base) {
        const char* kb_ = lds + base;
        const char* vb_ = lds + base + 8192;
        short8v k0a = *(const short8v*)(kb_ + rowb + kc0);
        short8v k0b = *(const short8v*)(kb_ + rowb + kc1);
        short8v k1a = *(const short8v*)(kb_ + 2048 + rowb + kc0);
        short8v k1b = *(const short8v*)(kb_ + 2048 + rowb + kc1);
        short8v k2a = *(const short8v*)(kb_ + 4096 + rowb + kc0);
        short8v k2b = *(const short8v*)(kb_ + 4096 + rowb + kc1);
        short8v k3a = *(const short8v*)(kb_ + 6144 + rowb + kc0);
        short8v k3b = *(const short8v*)(kb_ + 6144 + rowb + kc1);

        float4v sA0 = {}, sA1 = {}, sA2 = {}, sA3 = {};
        float4v sB0 = {}, sB1 = {}, sB2 = {}, sB3 = {};
        __builtin_amdgcn_s_setprio(1);
        sA0 = __builtin_amdgcn_mfma_f32_16x16x32_bf16(k0a, qfA0, sA0, 0, 0, 0);
        sA0 = __builtin_amdgcn_mfma_f32_16x16x32_bf16(k0b, qfA1, sA0, 0, 0, 0);
        sA1 = __builtin_amdgcn_mfma_f32_16x16x32_bf16(k1a, qfA0, sA1, 0, 0, 0);
        sA1 = __builtin_amdgcn_mfma_f32_16x16x32_bf16(k1b, qfA1, sA1, 0, 0, 0);
        sA2 = __builtin_amdgcn_mfma_f32_16x16x32_bf16(k2a, qfA0, sA2, 0, 0, 0);
        sA2 = __builtin_amdgcn_mfma_f32_16x16x32_bf16(k2b, qfA1, sA2, 0, 0, 0);
        sA3 = __builtin_amdgcn_mfma_f32_16x16x32_bf16(k3a, qfA0, sA3, 0, 0, 0);
        sA3 = __builtin_amdgcn_mfma_f32_16x16x32_bf16(k3b, qfA1, sA3, 0, 0, 0);
        sB0 = __builtin_amdgcn_mfma_f32_16x16x32_bf16(k0a, qfB0, sB0, 0, 0, 0);
        sB0 = __builtin_amdgcn_mfma_f32_16x16x32_bf16(k0b, qfB1, sB0, 0, 0, 0);
        sB1 = __builtin_amdgcn_mfma_f32_16x16x32_bf16(k1a, qfB0, sB1, 0, 0, 0);
        sB1 = __builtin_amdgcn_mfma_f32_16x16x32_bf16(k1b, qfB1, sB1, 0, 0, 0);
        sB2 = __builtin_amdgcn_mfma_f32_16x16x32_bf16(k2a, qfB0, sB2, 0, 0, 0);
        sB2 = __builtin_amdgcn_mfma_f32_16x16x32_bf16(k2b, qfB1, sB2, 0, 0, 0);
        sB3 = __builtin_amdgcn_mfma_f32_16x16x32_bf16(k3a, qfB0, sB3, 0, 0, 0);
        sB3 = __builtin_amdgcn_mfma_f32_16x16x32_bf16(k3b, qfB1, sB3, 0, 0, 0);
        __builtin_amdgcn_s_setprio(0);

        // issue V reads now; their LDS latency hides under the softmax VALU
        short8v v0a = *(const short8v*)(vb_ + rowb + vc0);
        short8v v0b = *(const short8v*)(vb_ + rowb + vc1);
        short8v v1a = *(const short8v*)(vb_ + 2048 + rowb + vc0);
        short8v v1b = *(const short8v*)(vb_ + 2048 + rowb + vc1);
        short8v v2a = *(const short8v*)(vb_ + 4096 + rowb + vc0);
        short8v v2b = *(const short8v*)(vb_ + 4096 + rowb + vc1);
        short8v v3a = *(const short8v*)(vb_ + 6144 + rowb + vc0);
        short8v v3b = *(const short8v*)(vb_ + 6144 + rowb + vc1);

        short8v pA0, pA1, pB0, pB1;
        softmax64(sA0, sA1, sA2, sA3, mA, lA, oaccA, pA0, pA1);
        softmax64(sB0, sB1, sB2, sB3, mB, lB, oaccB, pB0, pB1);

        __builtin_amdgcn_s_setprio(1);
        oaccA[0] = __builtin_amdgcn_mfma_f32_16x16x32_bf16(pA0, v0a, oaccA[0], 0, 0, 0);
        oaccA[0] = __builtin_amdgcn_mfma_f32_16x16x32_bf16(pA1, v0b, oaccA[0], 0, 0, 0);
        oaccB[0] = __builtin_amdgcn_mfma_f32_16x16x32_bf16(pB0, v0a, oaccB[0], 0, 0, 0);
        oaccB[0] = __builtin_amdgcn_mfma_f32_16x16x32_bf16(pB1, v0b, oaccB[0], 0, 0, 0);
        oaccA[1] = __builtin_amdgcn_mfma_f32_16x16x32_bf16(pA0, v1a, oaccA[1], 0, 0, 0);
        oaccA[1] = __builtin_amdgcn_mfma_f32_16x16x32_bf16(pA1, v1b, oaccA[1], 0, 0, 0);
        oaccB[1] = __builtin_amdgcn_mfma_f32_16x16x32_bf16(pB0, v1a, oaccB[1], 0, 0, 0);
        oaccB[1] = __builtin_amdgcn_mfma_f32_16x16x32_bf16(pB1, v1b, oaccB[1], 0, 0, 0);
        oaccA[2] = __builtin_amdgcn_mfma_f32_16x16x32_bf16(pA0, v2a, oaccA[2], 0, 0, 0);
        oaccA[2] = __builtin_amdgcn_mfma_f32_16x16x32_bf16(pA1, v2b, oaccA[2], 0, 0, 0);
        oaccB[2] = __builtin_amdgcn_mfma_f32_16x16x32_bf16(pB0, v2a, oaccB[2], 0, 0, 0);
        oaccB[2] = __builtin_amdgcn_mfma_f32_16x16x32_bf16(pB1, v2b, oaccB[2], 0, 0, 0);
        oaccA[3] = __builtin_amdgcn_mfma_f32_16x16x32_bf16(pA0, v3a, oaccA[3], 0, 0, 0);
        oaccA[3] = __builtin_amdgcn_mfma_f32_16x16x32_bf16(pA1, v3b, oaccA[3], 0, 0, 0);
        oaccB[3] = __builtin_amdgcn_mfma_f32_16x16x32_bf16(pB0, v3a, oaccB[3], 0, 0, 0);
        oaccB[3] = __builtin_amdgcn_mfma_f32_16x16x32_bf16(pB1, v3b, oaccB[3], 0, 0, 0);
        __builtin_amdgcn_s_setprio(0);
    };

    // ---- pipelined loop: counted vmcnt, never drained mid-loop ----
    stage(0, 0);
    for (int kt = 0; kt < T_ / 64; kt += 2) {
        stage(kt + 1, 16384);
        asm volatile("s_waitcnt vmcnt(4)" ::: "memory");   // buf0 (oldest 4) landed
        __builtin_amdgcn_s_barrier();
        compute(0);
        __builtin_amdgcn_s_barrier();                      // all waves done with buf0
        if (kt + 2 < T_ / 64) {
            stage(kt + 2, 0);
            asm volatile("s_waitcnt vmcnt(4)" ::: "memory"); // buf1 landed
        } else {
            asm volatile("s_waitcnt vmcnt(0)" ::: "memory");
        }
        __builtin_amdgcn_s_barrier();
        compute(16384);
        __builtin_amdgcn_s_barrier();                      // protect buf1 overwrite
    }

    // final cross-lane reduce of the deferred row-sum partials
    lA += __shfl_xor(lA, 16); lA += __shfl_xor(lA, 32);
    lB += __shfl_xor(lB, 16); lB += __shfl_xor(lB, 32);

    int b = bh >> 4, h = bh & 15;
    {
        float i0 = 1.f / __shfl(lA, g * 4 + 0), i1 = 1.f / __shfl(lA, g * 4 + 1);
        float i2 = 1.f / __shfl(lA, g * 4 + 2), i3 = 1.f / __shfl(lA, g * 4 + 3);
#pragma unroll
        for (int c = 0; c < 4; ++c) {
            size_t base = ((size_t)b * T_ + qb + g * 4) * E_ + h * 64 + c * 16 + r15;
            Ob[base]          = f2bf(oaccA[c][0] * i0);
            Ob[base + E_]     = f2bf(oaccA[c][1] * i1);
            Ob[base + 2 * E_] = f2bf(oaccA[c][2] * i2);
            Ob[base + 3 * E_] = f2bf(oaccA[c][3] * i3);
        }
    }
    {
        float i0 = 1.f / __shfl(lB, g * 4 + 0), i1 = 1.f / __shfl(lB, g * 4 + 1);
        float i2 = 1.f / __shfl(lB, g * 4 + 2), i3 = 1.f / __shfl(lB, g * 4 + 3);
#pragma unroll
        for (int c = 0; c < 4; ++c) {
            size_t base = ((size_t)b * T_ + qb + 16 + g * 4) * E_ + h * 64 + c * 16 + r15;
            Ob[base]          = f2bf(oaccB[c][0] * i0);
            Ob[base + E_]     = f2bf(oaccB[c][1] * i1);
            Ob[base + 2 * E_] = f2bf(oaccB[c][2] * i2);
            Ob[base + 3 * E_] = f2bf(oaccB[c][3] * i3);
        }
    }
}

extern "C" void kernel_launch(void* const* d_in, const int* in_sizes, int n_in,
                              void* d_out, int out_size, void* d_ws, size_t ws_size,
                              hipStream_t stream) {
    const float* query = (const float*)d_in[0];
    const float* Wqkv  = (const float*)d_in[1];
    const float* bqkv  = (const float*)d_in[2];
    const float* Wo    = (const float*)d_in[3];
    const float* bo    = (const float*)d_in[4];
    float* out = (float*)d_out;

    // workspace (bf16 elems), ~41 MB total. Ob aliases Xb (Xb dead after GEMM1).
    ushort* Xb    = (ushort*)d_ws;                        // M_*E_ (8 MB)
    ushort* Wqkvb = Xb + (size_t)M_ * E_;                 // F_*E_ (6 MB)
    ushort* Wob   = Wqkvb + (size_t)F_ * E_;              // E_*E_ (2 MB)
    ushort* QKVb  = Wob + (size_t)E_ * E_;                // 2*M_*E_ + B*H*D*VT_STRIDE
    ushort* Ob    = Xb;                                   // alias: [B*T][E]

    cvt_kernel<<<(M_ * E_ / 4 + 255) / 256, 256, 0, stream>>>(query, Xb, M_ * E_ / 4);
    cvt_kernel<<<(F_ * E_ / 4 + 255) / 256, 256, 0, stream>>>(Wqkv, Wqkvb, F_ * E_ / 4);
    cvt_kernel<<<(E_ * E_ / 4 + 255) / 256, 256, 0, stream>>>(Wo, Wob, E_ * E_ / 4);

    gemm_bt<0><<<dim3(M_ / 128, F_ / 128), 256, 0, stream>>>(Xb, Wqkvb, bqkv, QKVb, F_, E_);
    attn_kernel<<<(B_ * H_) * (T_ / 128), 256, 0, stream>>>(QKVb, Ob);
    gemm_bt<1><<<dim3(M_ / 128, E_ / 128), 256, 0, stream>>>(Ob, Wob, bo, out, E_, E_);
}